// Round 8
// baseline (1240.861 us; speedup 1.0000x reference)
//
#include <hip/hip_runtime.h>

// GCN 2-layer. R8: bucket-binned edges (128 dst/bucket) + LDS-accumulated gather.
// vs R7 (failed absmax 5.6e-2): gathers use wave-uniform direct entry reads instead
// of __shfl broadcast; bscan summed scalar. Everything else identical (bisection).

#define NBKT(n) (((n) + 127) >> 7)

// ---------------- degree ----------------
__global__ void deg_kernel(const int* __restrict__ dst, int E, int* __restrict__ deg) {
    int e = blockIdx.x * blockDim.x + threadIdx.x;
    if (e < E) atomicAdd(&deg[dst[e]], 1);
}

__global__ void dinv_kernel(const int* __restrict__ deg, float* __restrict__ dinv, int N) {
    int i = blockIdx.x * blockDim.x + threadIdx.x;
    if (i < N) dinv[i] = rsqrtf((float)deg[i] + 1.0f);  // +1 = self-loop
}

// ---------------- bucket offsets: boffs = exscan(per-bucket degree sums) ----------------
__global__ void bscan_kernel(const int* __restrict__ deg, int N, int nbk, int E,
                             int* __restrict__ boffs, int* __restrict__ gcursor) {
    __shared__ int s[1024];
    const int t = threadIdx.x;
    int sum = 0;
    if (t < nbk) {
        int base = t * 128;
        int lim = min(128, N - base);
        for (int i = 0; i < lim; ++i) sum += deg[base + i];
    }
    s[t] = sum;
    __syncthreads();
    for (int off = 1; off < 1024; off <<= 1) {
        int x = (t >= off) ? s[t - off] : 0;
        __syncthreads();
        s[t] += x;
        __syncthreads();
    }
    if (t < nbk) {
        int excl = s[t] - sum;
        boffs[t] = excl;
        gcursor[t] = excl;
    }
    if (t == 0) boffs[nbk] = E;
}

// ---------------- binfill: entries grouped by bucket (dst>>7), block-local runs ------
// entry = (src<<7) | (dst&127).
#define BF_CHUNK 16384
__global__ void __launch_bounds__(256) binfill_kernel(
        const int* __restrict__ src, const int* __restrict__ dst, int E, int nbk,
        int* __restrict__ gcursor, int* __restrict__ entries) {
    __shared__ int cnt[NBKT(100000)];
    __shared__ int gbase[NBKT(100000)];
    __shared__ int rank[NBKT(100000)];
    const int t = threadIdx.x;
    const int beg = blockIdx.x * BF_CHUNK;
    const int end = min(E, beg + BF_CHUNK);
    for (int b = t; b < nbk; b += 256) cnt[b] = 0;
    __syncthreads();
    for (int i = beg + t; i < end; i += 256) atomicAdd(&cnt[dst[i] >> 7], 1);
    __syncthreads();
    for (int b = t; b < nbk; b += 256) {
        int c = cnt[b];
        gbase[b] = c ? atomicAdd(&gcursor[b], c) : 0;
        rank[b] = 0;
    }
    __syncthreads();
    for (int i = beg + t; i < end; i += 256) {
        int d = dst[i];
        int b = d >> 7;
        int r = atomicAdd(&rank[b], 1);
        entries[gbase[b] + r] = (src[i] << 7) | (d & 127);
    }
}

// ---------------- LDS-tiled GEMM (R6, proven): out[r,c] = (A[r,:]@W[:,c]) * dinv[r] ----
#define FMA4(ACC, AV, WV) \
    ACC.x += (AV) * (WV).x; ACC.y += (AV) * (WV).y; ACC.z += (AV) * (WV).z; ACC.w += (AV) * (WV).w;

template <int K, int C, int BR>
__global__ void __launch_bounds__(256) gemm_tile_kernel(
        const float* __restrict__ A, const float* __restrict__ W,
        const float* __restrict__ dinv, float* __restrict__ out, int N) {
    constexpr int F4R = K / 4;
    constexpr int CG = C / 4;
    static_assert(256 / CG * 4 == BR, "geometry");
    __shared__ float Wl[K * C];
    __shared__ float Al[BR * K];

    const int t = threadIdx.x;
    for (int i = t; i < K * C / 4; i += 256) ((float4*)Wl)[i] = ((const float4*)W)[i];
    const int row0 = blockIdx.x * BR;
    for (int i = t; i < BR * F4R; i += 256) {
        int r = i / F4R, k4 = i % F4R;
        float4 v = make_float4(0.f, 0.f, 0.f, 0.f);
        if (row0 + r < N) v = ((const float4*)(A + (size_t)(row0 + r) * K))[k4];
        *(float4*)(Al + r * K + k4 * 4) = v;
    }
    __syncthreads();

    const int c0 = (t % CG) * 4;
    const int r0 = (t / CG) * 4;
    const float* Ab = Al + r0 * K;

    float4 acc0 = {0, 0, 0, 0}, acc1 = {0, 0, 0, 0}, acc2 = {0, 0, 0, 0}, acc3 = {0, 0, 0, 0};

#pragma unroll 2
    for (int k4 = 0; k4 < K / 4; ++k4) {
        float4 a0 = *(const float4*)(Ab + 0 * K + k4 * 4);
        float4 a1 = *(const float4*)(Ab + 1 * K + k4 * 4);
        float4 a2 = *(const float4*)(Ab + 2 * K + k4 * 4);
        float4 a3 = *(const float4*)(Ab + 3 * K + k4 * 4);
        float4 w0 = *(const float4*)(Wl + (k4 * 4 + 0) * C + c0);
        float4 w1 = *(const float4*)(Wl + (k4 * 4 + 1) * C + c0);
        float4 w2 = *(const float4*)(Wl + (k4 * 4 + 2) * C + c0);
        float4 w3 = *(const float4*)(Wl + (k4 * 4 + 3) * C + c0);
        FMA4(acc0, a0.x, w0) FMA4(acc1, a1.x, w0) FMA4(acc2, a2.x, w0) FMA4(acc3, a3.x, w0)
        FMA4(acc0, a0.y, w1) FMA4(acc1, a1.y, w1) FMA4(acc2, a2.y, w1) FMA4(acc3, a3.y, w1)
        FMA4(acc0, a0.z, w2) FMA4(acc1, a1.z, w2) FMA4(acc2, a2.z, w2) FMA4(acc3, a3.z, w2)
        FMA4(acc0, a0.w, w3) FMA4(acc1, a1.w, w3) FMA4(acc2, a2.w, w3) FMA4(acc3, a3.w, w3)
    }

    int row = row0 + r0;
    if (row + 3 < N) {
        float d0 = dinv[row], d1 = dinv[row + 1], d2 = dinv[row + 2], d3 = dinv[row + 3];
        float4 r;
        r.x = acc0.x * d0; r.y = acc0.y * d0; r.z = acc0.z * d0; r.w = acc0.w * d0;
        *(float4*)(out + (size_t)row * C + c0) = r;
        r.x = acc1.x * d1; r.y = acc1.y * d1; r.z = acc1.z * d1; r.w = acc1.w * d1;
        *(float4*)(out + (size_t)(row + 1) * C + c0) = r;
        r.x = acc2.x * d2; r.y = acc2.y * d2; r.z = acc2.z * d2; r.w = acc2.w * d2;
        *(float4*)(out + (size_t)(row + 2) * C + c0) = r;
        r.x = acc3.x * d3; r.y = acc3.y * d3; r.z = acc3.z * d3; r.w = acc3.w * d3;
        *(float4*)(out + (size_t)(row + 3) * C + c0) = r;
    } else {
        if (row < N) {
            float d = dinv[row];
            float4 r = {acc0.x * d, acc0.y * d, acc0.z * d, acc0.w * d};
            *(float4*)(out + (size_t)row * C + c0) = r;
        }
        if (row + 1 < N) {
            float d = dinv[row + 1];
            float4 r = {acc1.x * d, acc1.y * d, acc1.z * d, acc1.w * d};
            *(float4*)(out + (size_t)(row + 1) * C + c0) = r;
        }
        if (row + 2 < N) {
            float d = dinv[row + 2];
            float4 r = {acc2.x * d, acc2.y * d, acc2.z * d, acc2.w * d};
            *(float4*)(out + (size_t)(row + 2) * C + c0) = r;
        }
        if (row + 3 < N) {
            float d = dinv[row + 3];
            float4 r = {acc3.x * d, acc3.y * d, acc3.z * d, acc3.w * d};
            *(float4*)(out + (size_t)(row + 3) * C + c0) = r;
        }
    }
}

// ---------------- bucket gather, C=64: one block per 128-node bucket ----------------
// Wave-uniform entry reads (scalar-cache); 64 lanes = 64 features per edge.
template <bool RELU>
__global__ void __launch_bounds__(256) gather_b64(
        const float* __restrict__ hs, const float* __restrict__ dinv,
        const int* __restrict__ boffs, const int* __restrict__ entries,
        const float* __restrict__ bias, float* __restrict__ out, int N) {
    __shared__ float acc[128 * 64];
    const int t = threadIdx.x;
    for (int i = t; i < 128 * 64 / 4; i += 256) ((float4*)acc)[i] = make_float4(0, 0, 0, 0);
    __syncthreads();
    const int lane = t & 63;
    const int wave = t >> 6;
    const int beg = boffs[blockIdx.x];
    const int end = boffs[blockIdx.x + 1];
    for (int base = beg + wave * 64; base < end; base += 256) {
        const int it = min(64, end - base);
#pragma unroll 4
        for (int j = 0; j < it; ++j) {
            int e = entries[base + j];  // wave-uniform address -> scalar load
            float v = hs[(size_t)((unsigned)e >> 7) * 64 + lane];
            atomicAdd(&acc[(e & 127) * 64 + lane], v);
        }
    }
    __syncthreads();
    const int node0 = blockIdx.x * 128;
    for (int i = t; i < 128 * 16; i += 256) {  // float4 index: 16 per node row
        int n = i >> 4, f4 = i & 15;
        int node = node0 + n;
        if (node < N) {
            float d = dinv[node];
            float4 a = ((const float4*)acc)[i];
            float4 h = ((const float4*)(hs + (size_t)node * 64))[f4];
            float4 bv = ((const float4*)bias)[f4];
            float4 r;
            r.x = (a.x + h.x) * d + bv.x;
            r.y = (a.y + h.y) * d + bv.y;
            r.z = (a.z + h.z) * d + bv.z;
            r.w = (a.w + h.w) * d + bv.w;
            if (RELU) {
                r.x = fmaxf(r.x, 0.f); r.y = fmaxf(r.y, 0.f);
                r.z = fmaxf(r.z, 0.f); r.w = fmaxf(r.w, 0.f);
            }
            *(float4*)(out + (size_t)node * 64 + f4 * 4) = r;
        }
    }
}

// ---------------- bucket gather, C=32: 2 edges per wave-step (half = lane>>5) --------
__global__ void __launch_bounds__(256) gather_b32(
        const float* __restrict__ hs, const float* __restrict__ dinv,
        const int* __restrict__ boffs, const int* __restrict__ entries,
        const float* __restrict__ bias, float* __restrict__ out, int N) {
    __shared__ float acc[128 * 32];
    const int t = threadIdx.x;
    for (int i = t; i < 128 * 32 / 4; i += 256) ((float4*)acc)[i] = make_float4(0, 0, 0, 0);
    __syncthreads();
    const int lane = t & 63;
    const int wave = t >> 6;
    const int feat = lane & 31;
    const int half = lane >> 5;
    const int beg = boffs[blockIdx.x];
    const int end = boffs[blockIdx.x + 1];
    for (int base = beg + wave * 64; base < end; base += 256) {
        const int it = min(64, end - base);
        int j = 0;
#pragma unroll 4
        for (; j + 1 < it; j += 2) {
            int e = entries[base + j + half];  // uniform within each 32-lane half
            float v = hs[(size_t)((unsigned)e >> 7) * 32 + feat];
            atomicAdd(&acc[(e & 127) * 32 + feat], v);
        }
        if (j < it && half == 0) {
            int e = entries[base + j];
            float v = hs[(size_t)((unsigned)e >> 7) * 32 + feat];
            atomicAdd(&acc[(e & 127) * 32 + feat], v);
        }
    }
    __syncthreads();
    const int node0 = blockIdx.x * 128;
    for (int i = t; i < 128 * 8; i += 256) {  // float4 index: 8 per node row
        int n = i >> 3, f4 = i & 7;
        int node = node0 + n;
        if (node < N) {
            float d = dinv[node];
            float4 a = ((const float4*)acc)[i];
            float4 h = ((const float4*)(hs + (size_t)node * 32))[f4];
            float4 bv = ((const float4*)bias)[f4];
            float4 r;
            r.x = (a.x + h.x) * d + bv.x;
            r.y = (a.y + h.y) * d + bv.y;
            r.z = (a.z + h.z) * d + bv.z;
            r.w = (a.w + h.w) * d + bv.w;
            *(float4*)(out + (size_t)node * 32 + f4 * 4) = r;
        }
    }
}

extern "C" void kernel_launch(void* const* d_in, const int* in_sizes, int n_in,
                              void* d_out, int out_size, void* d_ws, size_t ws_size,
                              hipStream_t stream) {
    const float* x = (const float*)d_in[0];
    const int* ei = (const int*)d_in[1];
    const float* W1 = (const float*)d_in[2];
    const float* b1 = (const float*)d_in[3];
    const float* W2 = (const float*)d_in[4];
    const float* b2 = (const float*)d_in[5];

    const int N = in_sizes[0] / 128;  // 100000
    const int E = in_sizes[1] / 2;    // 1600000
    const int* src = ei;
    const int* dst = ei + E;
    const int nbk = NBKT(N);          // 782 buckets of 128 dst nodes

    // workspace layout (4-byte elements)
    int* deg = (int*)d_ws;                          // N
    float* dinv = (float*)(deg + ((N + 255) & ~255));  // N
    int* boffs = (int*)(dinv + ((N + 255) & ~255)); // nbk+1 (pad 1024)
    int* gcursor = boffs + 1024;                    // nbk (pad 1024)
    int* entries = gcursor + 1024;                  // E
    float* h1s = (float*)(entries + ((E + 255) & ~255));  // N*64
    float* h2 = h1s + (size_t)N * 64;               // N*64
    float* h3s = h1s;                               // reuse (N*32)
    float* out = (float*)d_out;

    // 1) degrees -> dinv ; bucket offsets
    hipMemsetAsync(deg, 0, (size_t)N * 4, stream);
    deg_kernel<<<(E + 255) / 256, 256, 0, stream>>>(dst, E, deg);
    dinv_kernel<<<(N + 255) / 256, 256, 0, stream>>>(deg, dinv, N);
    bscan_kernel<<<1, 1024, 0, stream>>>(deg, N, nbk, E, boffs, gcursor);

    // 2) bin edges by bucket (block-local runs -> no line amplification)
    binfill_kernel<<<(E + BF_CHUNK - 1) / BF_CHUNK, 256, 0, stream>>>(src, dst, E, nbk, gcursor, entries);

    // 3) h1s = (x @ W1) * dinv
    gemm_tile_kernel<128, 64, 64><<<(N + 63) / 64, 256, 0, stream>>>(x, W1, dinv, h1s, N);

    // 4) h2 = relu(dinv*(gather h1s) + b1)
    gather_b64<true><<<nbk, 256, 0, stream>>>(h1s, dinv, boffs, entries, b1, h2, N);

    // 5) h3s = (h2 @ W2) * dinv
    gemm_tile_kernel<64, 32, 128><<<(N + 127) / 128, 256, 0, stream>>>(h2, W2, dinv, h3s, N);

    // 6) out = dinv*(gather h3s) + b2
    gather_b32<<<nbk, 256, 0, stream>>>(h3s, dinv, boffs, entries, b2, out, N);
}

// Round 9
// 380.031 us; speedup vs baseline: 3.2652x; 3.2652x over previous
//
#include <hip/hip_runtime.h>

// GCN 2-layer. R9: node-exact CSR gathers (R3/R6, proven fast) + two-phase CSR build:
//   binfill (R8, proven): edges -> 128-node buckets, block-local runs (no write amp)
//   bucket2csr (new): per-bucket LDS counting sort -> node-exact csr_src + offs
// Replaces R6's direct fill (105MB written for 6.4MB array) and R8's latency-serial
// bucket gather (687us).

#define NBKT(n) (((n) + 127) >> 7)

// ---------------- degree ----------------
__global__ void deg_kernel(const int* __restrict__ dst, int E, int* __restrict__ deg) {
    int e = blockIdx.x * blockDim.x + threadIdx.x;
    if (e < E) atomicAdd(&deg[dst[e]], 1);
}

__global__ void dinv_kernel(const int* __restrict__ deg, float* __restrict__ dinv, int N) {
    int i = blockIdx.x * blockDim.x + threadIdx.x;
    if (i < N) dinv[i] = rsqrtf((float)deg[i] + 1.0f);  // +1 = self-loop
}

// ---------------- bucket offsets: boffs = exscan(per-bucket degree sums) (R8 proven) --
__global__ void bscan_kernel(const int* __restrict__ deg, int N, int nbk, int E,
                             int* __restrict__ boffs, int* __restrict__ gcursor) {
    __shared__ int s[1024];
    const int t = threadIdx.x;
    int sum = 0;
    if (t < nbk) {
        int base = t * 128;
        int lim = min(128, N - base);
        for (int i = 0; i < lim; ++i) sum += deg[base + i];
    }
    s[t] = sum;
    __syncthreads();
    for (int off = 1; off < 1024; off <<= 1) {
        int x = (t >= off) ? s[t - off] : 0;
        __syncthreads();
        s[t] += x;
        __syncthreads();
    }
    if (t < nbk) {
        int excl = s[t] - sum;
        boffs[t] = excl;
        gcursor[t] = excl;
    }
    if (t == 0) boffs[nbk] = E;
}

// ---------------- binfill: entries grouped by bucket (dst>>7) (R8 proven) ------------
// entry = (src<<7) | (dst&127).
#define BF_CHUNK 16384
__global__ void __launch_bounds__(256) binfill_kernel(
        const int* __restrict__ src, const int* __restrict__ dst, int E, int nbk,
        int* __restrict__ gcursor, int* __restrict__ entries) {
    __shared__ int cnt[NBKT(100000)];
    __shared__ int gbase[NBKT(100000)];
    __shared__ int rank[NBKT(100000)];
    const int t = threadIdx.x;
    const int beg = blockIdx.x * BF_CHUNK;
    const int end = min(E, beg + BF_CHUNK);
    for (int b = t; b < nbk; b += 256) cnt[b] = 0;
    __syncthreads();
    for (int i = beg + t; i < end; i += 256) atomicAdd(&cnt[dst[i] >> 7], 1);
    __syncthreads();
    for (int b = t; b < nbk; b += 256) {
        int c = cnt[b];
        gbase[b] = c ? atomicAdd(&gcursor[b], c) : 0;
        rank[b] = 0;
    }
    __syncthreads();
    for (int i = beg + t; i < end; i += 256) {
        int d = dst[i];
        int b = d >> 7;
        int r = atomicAdd(&rank[b], 1);
        entries[gbase[b] + r] = (src[i] << 7) | (d & 127);
    }
}

// ---------------- bucket2csr: counting-sort each bucket to node-exact CSR ------------
// One block per bucket. Emits offs[node] (global exscan) and csr_src in node order.
__global__ void __launch_bounds__(256) bucket2csr_kernel(
        const int* __restrict__ entries, const int* __restrict__ boffs, int nbk,
        int* __restrict__ offs, int* __restrict__ csr_src, int N, int E) {
    __shared__ int cnt[128];
    __shared__ int s[128];     // inclusive scan of cnt
    __shared__ int rank[128];
    const int t = threadIdx.x;
    const int b = blockIdx.x;
    const int beg = boffs[b];
    const int end = boffs[b + 1];
    if (t < 128) { cnt[t] = 0; rank[t] = 0; }
    __syncthreads();
    for (int i = beg + t; i < end; i += 256) atomicAdd(&cnt[entries[i] & 127], 1);
    __syncthreads();
    if (t < 128) s[t] = cnt[t];
    __syncthreads();
    for (int off = 1; off < 128; off <<= 1) {
        int x = 0;
        if (t < 128 && t >= off) x = s[t - off];
        __syncthreads();
        if (t < 128) s[t] += x;
        __syncthreads();
    }
    // nodeoff (exclusive) = s[t] - cnt[t]
    const int node0 = b * 128;
    if (t < 128 && node0 + t < N) offs[node0 + t] = beg + s[t] - cnt[t];
    if (b == 0 && t == 0) offs[N] = E;
    __syncthreads();
    for (int i = beg + t; i < end; i += 256) {
        int e = entries[i];
        int d = e & 127;
        int r = atomicAdd(&rank[d], 1);
        csr_src[beg + s[d] - cnt[d] + r] = (int)((unsigned)e >> 7);
    }
}

// ---------------- LDS-tiled GEMM (R6 proven): out[r,c] = (A[r,:]@W[:,c]) * dinv[r] ----
#define FMA4(ACC, AV, WV) \
    ACC.x += (AV) * (WV).x; ACC.y += (AV) * (WV).y; ACC.z += (AV) * (WV).z; ACC.w += (AV) * (WV).w;

template <int K, int C, int BR>
__global__ void __launch_bounds__(256) gemm_tile_kernel(
        const float* __restrict__ A, const float* __restrict__ W,
        const float* __restrict__ dinv, float* __restrict__ out, int N) {
    constexpr int F4R = K / 4;
    constexpr int CG = C / 4;
    static_assert(256 / CG * 4 == BR, "geometry");
    __shared__ float Wl[K * C];
    __shared__ float Al[BR * K];

    const int t = threadIdx.x;
    for (int i = t; i < K * C / 4; i += 256) ((float4*)Wl)[i] = ((const float4*)W)[i];
    const int row0 = blockIdx.x * BR;
    for (int i = t; i < BR * F4R; i += 256) {
        int r = i / F4R, k4 = i % F4R;
        float4 v = make_float4(0.f, 0.f, 0.f, 0.f);
        if (row0 + r < N) v = ((const float4*)(A + (size_t)(row0 + r) * K))[k4];
        *(float4*)(Al + r * K + k4 * 4) = v;
    }
    __syncthreads();

    const int c0 = (t % CG) * 4;
    const int r0 = (t / CG) * 4;
    const float* Ab = Al + r0 * K;

    float4 acc0 = {0, 0, 0, 0}, acc1 = {0, 0, 0, 0}, acc2 = {0, 0, 0, 0}, acc3 = {0, 0, 0, 0};

#pragma unroll 2
    for (int k4 = 0; k4 < K / 4; ++k4) {
        float4 a0 = *(const float4*)(Ab + 0 * K + k4 * 4);
        float4 a1 = *(const float4*)(Ab + 1 * K + k4 * 4);
        float4 a2 = *(const float4*)(Ab + 2 * K + k4 * 4);
        float4 a3 = *(const float4*)(Ab + 3 * K + k4 * 4);
        float4 w0 = *(const float4*)(Wl + (k4 * 4 + 0) * C + c0);
        float4 w1 = *(const float4*)(Wl + (k4 * 4 + 1) * C + c0);
        float4 w2 = *(const float4*)(Wl + (k4 * 4 + 2) * C + c0);
        float4 w3 = *(const float4*)(Wl + (k4 * 4 + 3) * C + c0);
        FMA4(acc0, a0.x, w0) FMA4(acc1, a1.x, w0) FMA4(acc2, a2.x, w0) FMA4(acc3, a3.x, w0)
        FMA4(acc0, a0.y, w1) FMA4(acc1, a1.y, w1) FMA4(acc2, a2.y, w1) FMA4(acc3, a3.y, w1)
        FMA4(acc0, a0.z, w2) FMA4(acc1, a1.z, w2) FMA4(acc2, a2.z, w2) FMA4(acc3, a3.z, w2)
        FMA4(acc0, a0.w, w3) FMA4(acc1, a1.w, w3) FMA4(acc2, a2.w, w3) FMA4(acc3, a3.w, w3)
    }

    int row = row0 + r0;
    if (row + 3 < N) {
        float d0 = dinv[row], d1 = dinv[row + 1], d2 = dinv[row + 2], d3 = dinv[row + 3];
        float4 r;
        r.x = acc0.x * d0; r.y = acc0.y * d0; r.z = acc0.z * d0; r.w = acc0.w * d0;
        *(float4*)(out + (size_t)row * C + c0) = r;
        r.x = acc1.x * d1; r.y = acc1.y * d1; r.z = acc1.z * d1; r.w = acc1.w * d1;
        *(float4*)(out + (size_t)(row + 1) * C + c0) = r;
        r.x = acc2.x * d2; r.y = acc2.y * d2; r.z = acc2.z * d2; r.w = acc2.w * d2;
        *(float4*)(out + (size_t)(row + 2) * C + c0) = r;
        r.x = acc3.x * d3; r.y = acc3.y * d3; r.z = acc3.z * d3; r.w = acc3.w * d3;
        *(float4*)(out + (size_t)(row + 3) * C + c0) = r;
    } else {
        if (row < N) {
            float d = dinv[row];
            float4 r = {acc0.x * d, acc0.y * d, acc0.z * d, acc0.w * d};
            *(float4*)(out + (size_t)row * C + c0) = r;
        }
        if (row + 1 < N) {
            float d = dinv[row + 1];
            float4 r = {acc1.x * d, acc1.y * d, acc1.z * d, acc1.w * d};
            *(float4*)(out + (size_t)(row + 1) * C + c0) = r;
        }
        if (row + 2 < N) {
            float d = dinv[row + 2];
            float4 r = {acc2.x * d, acc2.y * d, acc2.z * d, acc2.w * d};
            *(float4*)(out + (size_t)(row + 2) * C + c0) = r;
        }
        if (row + 3 < N) {
            float d = dinv[row + 3];
            float4 r = {acc3.x * d, acc3.y * d, acc3.z * d, acc3.w * d};
            *(float4*)(out + (size_t)(row + 3) * C + c0) = r;
        }
    }
}

// ---------------- per-node gather (R3/R6 proven): out[d]=dinv[d]*(sum hs[nbr]+hs[d])+b
template <int C, bool RELU>
__global__ void gather_kernel(const float* __restrict__ hs, const float* __restrict__ dinv,
                              const int* __restrict__ offs, const int* __restrict__ csr_src,
                              const float* __restrict__ b, float* __restrict__ out, int N) {
    int gtid = blockIdx.x * blockDim.x + threadIdx.x;
    int lane = gtid % C;
    int d = gtid / C;
    if (d >= N) return;
    float acc = hs[(size_t)d * C + lane];  // self-loop term
    int beg = offs[d];
    int end = offs[d + 1];
    int j = beg;
    for (; j + 1 < end; j += 2) {
        int s0 = csr_src[j];
        int s1 = csr_src[j + 1];
        float v0 = hs[(size_t)s0 * C + lane];
        float v1 = hs[(size_t)s1 * C + lane];
        acc += v0;
        acc += v1;
    }
    if (j < end) acc += hs[(size_t)csr_src[j] * C + lane];
    float r = acc * dinv[d] + b[lane];
    if (RELU) r = fmaxf(r, 0.f);
    out[(size_t)d * C + lane] = r;
}

extern "C" void kernel_launch(void* const* d_in, const int* in_sizes, int n_in,
                              void* d_out, int out_size, void* d_ws, size_t ws_size,
                              hipStream_t stream) {
    const float* x = (const float*)d_in[0];
    const int* ei = (const int*)d_in[1];
    const float* W1 = (const float*)d_in[2];
    const float* b1 = (const float*)d_in[3];
    const float* W2 = (const float*)d_in[4];
    const float* b2 = (const float*)d_in[5];

    const int N = in_sizes[0] / 128;  // 100000
    const int E = in_sizes[1] / 2;    // 1600000
    const int* src = ei;
    const int* dst = ei + E;
    const int nbk = NBKT(N);          // 782 buckets of 128 dst nodes

    // workspace layout (4-byte elements)
    int* deg = (int*)d_ws;                             // N
    float* dinv = (float*)(deg + ((N + 255) & ~255));  // N
    int* boffs = (int*)(dinv + ((N + 255) & ~255));    // nbk+1 (pad 1024)
    int* gcursor = boffs + 1024;                       // nbk (pad 1024)
    int* offs = gcursor + 1024;                        // N+1
    int* entries = offs + ((N + 1 + 255) & ~255);      // E
    int* csr_src = entries + ((E + 255) & ~255);       // E
    float* h1s = (float*)(csr_src + ((E + 255) & ~255));  // N*64
    float* h2 = h1s + (size_t)N * 64;                  // N*64
    float* h3s = h1s;                                  // reuse (N*32)
    float* out = (float*)d_out;

    // 1) degrees -> dinv ; bucket offsets
    hipMemsetAsync(deg, 0, (size_t)N * 4, stream);
    deg_kernel<<<(E + 255) / 256, 256, 0, stream>>>(dst, E, deg);
    dinv_kernel<<<(N + 255) / 256, 256, 0, stream>>>(deg, dinv, N);
    bscan_kernel<<<1, 1024, 0, stream>>>(deg, N, nbk, E, boffs, gcursor);

    // 2) two-phase node-exact CSR build
    binfill_kernel<<<(E + BF_CHUNK - 1) / BF_CHUNK, 256, 0, stream>>>(src, dst, E, nbk, gcursor, entries);
    bucket2csr_kernel<<<nbk, 256, 0, stream>>>(entries, boffs, nbk, offs, csr_src, N, E);

    // 3) h1s = (x @ W1) * dinv
    gemm_tile_kernel<128, 64, 64><<<(N + 63) / 64, 256, 0, stream>>>(x, W1, dinv, h1s, N);

    // 4) h2 = relu(dinv*(gather h1s) + b1)
    gather_kernel<64, true><<<(N * 64 + 255) / 256, 256, 0, stream>>>(h1s, dinv, offs, csr_src, b1, h2, N);

    // 5) h3s = (h2 @ W2) * dinv
    gemm_tile_kernel<64, 32, 128><<<(N + 127) / 128, 256, 0, stream>>>(h2, W2, dinv, h3s, N);

    // 6) out = dinv*(gather h3s) + b2
    gather_kernel<32, false><<<(N * 32 + 255) / 256, 256, 0, stream>>>(h3s, dinv, offs, csr_src, b2, out, N);
}

// Round 10
// 330.598 us; speedup vs baseline: 3.7534x; 1.1495x over previous
//
#include <hip/hip_runtime.h>

// GCN 2-layer. R10: gather tables in bf16 (h1s 25.6->12.8MB, h3s 12.8->6.4MB) to cut
// the gather's L2-capacity-miss refetch (R9: 190MB fetched for a 25.6MB table);
// 4-wide neighbor unroll for MLP. Accumulation stays fp32; h2 (GEMM2 input) fp32.

#define NBKT(n) (((n) + 127) >> 7)

__device__ inline float bf2f(unsigned short u) {
    union { unsigned int i; float f; } v;
    v.i = ((unsigned int)u) << 16;
    return v.f;
}
__device__ inline unsigned short f2bf(float f) {
    union { float f; unsigned int i; } v;
    v.f = f;
    unsigned int u = v.i;
    return (unsigned short)((u + 0x7fff + ((u >> 16) & 1)) >> 16);  // RTN-even
}

// ---------------- degree ----------------
__global__ void deg_kernel(const int* __restrict__ dst, int E, int* __restrict__ deg) {
    int e = blockIdx.x * blockDim.x + threadIdx.x;
    if (e < E) atomicAdd(&deg[dst[e]], 1);
}

__global__ void dinv_kernel(const int* __restrict__ deg, float* __restrict__ dinv, int N) {
    int i = blockIdx.x * blockDim.x + threadIdx.x;
    if (i < N) dinv[i] = rsqrtf((float)deg[i] + 1.0f);  // +1 = self-loop
}

// ---------------- bucket offsets (R8 proven) ----------------
__global__ void bscan_kernel(const int* __restrict__ deg, int N, int nbk, int E,
                             int* __restrict__ boffs, int* __restrict__ gcursor) {
    __shared__ int s[1024];
    const int t = threadIdx.x;
    int sum = 0;
    if (t < nbk) {
        int base = t * 128;
        int lim = min(128, N - base);
        for (int i = 0; i < lim; ++i) sum += deg[base + i];
    }
    s[t] = sum;
    __syncthreads();
    for (int off = 1; off < 1024; off <<= 1) {
        int x = (t >= off) ? s[t - off] : 0;
        __syncthreads();
        s[t] += x;
        __syncthreads();
    }
    if (t < nbk) {
        int excl = s[t] - sum;
        boffs[t] = excl;
        gcursor[t] = excl;
    }
    if (t == 0) boffs[nbk] = E;
}

// ---------------- binfill (R8 proven): entry = (src<<7) | (dst&127) ----------------
#define BF_CHUNK 16384
__global__ void __launch_bounds__(256) binfill_kernel(
        const int* __restrict__ src, const int* __restrict__ dst, int E, int nbk,
        int* __restrict__ gcursor, int* __restrict__ entries) {
    __shared__ int cnt[NBKT(100000)];
    __shared__ int gbase[NBKT(100000)];
    __shared__ int rank[NBKT(100000)];
    const int t = threadIdx.x;
    const int beg = blockIdx.x * BF_CHUNK;
    const int end = min(E, beg + BF_CHUNK);
    for (int b = t; b < nbk; b += 256) cnt[b] = 0;
    __syncthreads();
    for (int i = beg + t; i < end; i += 256) atomicAdd(&cnt[dst[i] >> 7], 1);
    __syncthreads();
    for (int b = t; b < nbk; b += 256) {
        int c = cnt[b];
        gbase[b] = c ? atomicAdd(&gcursor[b], c) : 0;
        rank[b] = 0;
    }
    __syncthreads();
    for (int i = beg + t; i < end; i += 256) {
        int d = dst[i];
        int b = d >> 7;
        int r = atomicAdd(&rank[b], 1);
        entries[gbase[b] + r] = (src[i] << 7) | (d & 127);
    }
}

// ---------------- bucket2csr (R9 proven) ----------------
__global__ void __launch_bounds__(256) bucket2csr_kernel(
        const int* __restrict__ entries, const int* __restrict__ boffs, int nbk,
        int* __restrict__ offs, int* __restrict__ csr_src, int N, int E) {
    __shared__ int cnt[128];
    __shared__ int s[128];
    __shared__ int rank[128];
    const int t = threadIdx.x;
    const int b = blockIdx.x;
    const int beg = boffs[b];
    const int end = boffs[b + 1];
    if (t < 128) { cnt[t] = 0; rank[t] = 0; }
    __syncthreads();
    for (int i = beg + t; i < end; i += 256) atomicAdd(&cnt[entries[i] & 127], 1);
    __syncthreads();
    if (t < 128) s[t] = cnt[t];
    __syncthreads();
    for (int off = 1; off < 128; off <<= 1) {
        int x = 0;
        if (t < 128 && t >= off) x = s[t - off];
        __syncthreads();
        if (t < 128) s[t] += x;
        __syncthreads();
    }
    const int node0 = b * 128;
    if (t < 128 && node0 + t < N) offs[node0 + t] = beg + s[t] - cnt[t];
    if (b == 0 && t == 0) offs[N] = E;
    __syncthreads();
    for (int i = beg + t; i < end; i += 256) {
        int e = entries[i];
        int d = e & 127;
        int r = atomicAdd(&rank[d], 1);
        csr_src[beg + s[d] - cnt[d] + r] = (int)((unsigned)e >> 7);
    }
}

// ---------------- LDS-tiled GEMM (R6 proven), bf16-out option ----------------
#define FMA4(ACC, AV, WV) \
    ACC.x += (AV) * (WV).x; ACC.y += (AV) * (WV).y; ACC.z += (AV) * (WV).z; ACC.w += (AV) * (WV).w;

template <int K, int C, int BR, bool BF16OUT>
__global__ void __launch_bounds__(256) gemm_tile_kernel(
        const float* __restrict__ A, const float* __restrict__ W,
        const float* __restrict__ dinv, void* __restrict__ outv, int N) {
    constexpr int F4R = K / 4;
    constexpr int CG = C / 4;
    static_assert(256 / CG * 4 == BR, "geometry");
    __shared__ float Wl[K * C];
    __shared__ float Al[BR * K];

    const int t = threadIdx.x;
    for (int i = t; i < K * C / 4; i += 256) ((float4*)Wl)[i] = ((const float4*)W)[i];
    const int row0 = blockIdx.x * BR;
    for (int i = t; i < BR * F4R; i += 256) {
        int r = i / F4R, k4 = i % F4R;
        float4 v = make_float4(0.f, 0.f, 0.f, 0.f);
        if (row0 + r < N) v = ((const float4*)(A + (size_t)(row0 + r) * K))[k4];
        *(float4*)(Al + r * K + k4 * 4) = v;
    }
    __syncthreads();

    const int c0 = (t % CG) * 4;
    const int r0 = (t / CG) * 4;
    const float* Ab = Al + r0 * K;

    float4 acc0 = {0, 0, 0, 0}, acc1 = {0, 0, 0, 0}, acc2 = {0, 0, 0, 0}, acc3 = {0, 0, 0, 0};

#pragma unroll 2
    for (int k4 = 0; k4 < K / 4; ++k4) {
        float4 a0 = *(const float4*)(Ab + 0 * K + k4 * 4);
        float4 a1 = *(const float4*)(Ab + 1 * K + k4 * 4);
        float4 a2 = *(const float4*)(Ab + 2 * K + k4 * 4);
        float4 a3 = *(const float4*)(Ab + 3 * K + k4 * 4);
        float4 w0 = *(const float4*)(Wl + (k4 * 4 + 0) * C + c0);
        float4 w1 = *(const float4*)(Wl + (k4 * 4 + 1) * C + c0);
        float4 w2 = *(const float4*)(Wl + (k4 * 4 + 2) * C + c0);
        float4 w3 = *(const float4*)(Wl + (k4 * 4 + 3) * C + c0);
        FMA4(acc0, a0.x, w0) FMA4(acc1, a1.x, w0) FMA4(acc2, a2.x, w0) FMA4(acc3, a3.x, w0)
        FMA4(acc0, a0.y, w1) FMA4(acc1, a1.y, w1) FMA4(acc2, a2.y, w1) FMA4(acc3, a3.y, w1)
        FMA4(acc0, a0.z, w2) FMA4(acc1, a1.z, w2) FMA4(acc2, a2.z, w2) FMA4(acc3, a3.z, w2)
        FMA4(acc0, a0.w, w3) FMA4(acc1, a1.w, w3) FMA4(acc2, a2.w, w3) FMA4(acc3, a3.w, w3)
    }

    const int row = row0 + r0;
#pragma unroll
    for (int i = 0; i < 4; ++i) {
        int rr = row + i;
        if (rr < N) {
            float d = dinv[rr];
            float4 fr = (i == 0) ? acc0 : (i == 1) ? acc1 : (i == 2) ? acc2 : acc3;
            fr.x *= d; fr.y *= d; fr.z *= d; fr.w *= d;
            if (BF16OUT) {
                ushort4 o;
                o.x = f2bf(fr.x); o.y = f2bf(fr.y); o.z = f2bf(fr.z); o.w = f2bf(fr.w);
                *(ushort4*)((unsigned short*)outv + (size_t)rr * C + c0) = o;
            } else {
                *(float4*)((float*)outv + (size_t)rr * C + c0) = fr;
            }
        }
    }
}

// ---------------- per-node gather from bf16 table ----------------
// out[d] = dinv[d]*(sum_{s in N(d)} hs[s] + hs[d]) + b, optional relu. fp32 out.
template <int C, bool RELU>
__global__ void gather_bf16_kernel(
        const unsigned short* __restrict__ hs, const float* __restrict__ dinv,
        const int* __restrict__ offs, const int* __restrict__ csr_src,
        const float* __restrict__ b, float* __restrict__ out, int N) {
    int gtid = blockIdx.x * blockDim.x + threadIdx.x;
    int lane = gtid % C;
    int d = gtid / C;
    if (d >= N) return;
    float acc = bf2f(hs[(size_t)d * C + lane]);  // self-loop term
    int beg = offs[d];
    int end = offs[d + 1];
    int j = beg;
    for (; j + 3 < end; j += 4) {
        int s0 = csr_src[j];
        int s1 = csr_src[j + 1];
        int s2 = csr_src[j + 2];
        int s3 = csr_src[j + 3];
        float v0 = bf2f(hs[(size_t)s0 * C + lane]);
        float v1 = bf2f(hs[(size_t)s1 * C + lane]);
        float v2 = bf2f(hs[(size_t)s2 * C + lane]);
        float v3 = bf2f(hs[(size_t)s3 * C + lane]);
        acc += v0 + v1 + v2 + v3;
    }
    for (; j < end; ++j) acc += bf2f(hs[(size_t)csr_src[j] * C + lane]);
    float r = acc * dinv[d] + b[lane];
    if (RELU) r = fmaxf(r, 0.f);
    out[(size_t)d * C + lane] = r;
}

extern "C" void kernel_launch(void* const* d_in, const int* in_sizes, int n_in,
                              void* d_out, int out_size, void* d_ws, size_t ws_size,
                              hipStream_t stream) {
    const float* x = (const float*)d_in[0];
    const int* ei = (const int*)d_in[1];
    const float* W1 = (const float*)d_in[2];
    const float* b1 = (const float*)d_in[3];
    const float* W2 = (const float*)d_in[4];
    const float* b2 = (const float*)d_in[5];

    const int N = in_sizes[0] / 128;  // 100000
    const int E = in_sizes[1] / 2;    // 1600000
    const int* src = ei;
    const int* dst = ei + E;
    const int nbk = NBKT(N);          // 782 buckets of 128 dst nodes

    // workspace layout (4-byte units unless noted)
    int* deg = (int*)d_ws;                             // N
    float* dinv = (float*)(deg + ((N + 255) & ~255));  // N
    int* boffs = (int*)(dinv + ((N + 255) & ~255));    // nbk+1 (pad 1024)
    int* gcursor = boffs + 1024;                       // nbk (pad 1024)
    int* offs = gcursor + 1024;                        // N+1
    int* entries = offs + ((N + 1 + 255) & ~255);      // E
    int* csr_src = entries + ((E + 255) & ~255);       // E
    unsigned short* h1s = (unsigned short*)(csr_src + ((E + 255) & ~255));  // N*64 bf16
    float* h2 = (float*)(h1s + (size_t)N * 64);        // N*64 fp32
    unsigned short* h3s = h1s;                         // reuse (N*32 bf16)
    float* out = (float*)d_out;

    // 1) degrees -> dinv ; bucket offsets
    hipMemsetAsync(deg, 0, (size_t)N * 4, stream);
    deg_kernel<<<(E + 255) / 256, 256, 0, stream>>>(dst, E, deg);
    dinv_kernel<<<(N + 255) / 256, 256, 0, stream>>>(deg, dinv, N);
    bscan_kernel<<<1, 1024, 0, stream>>>(deg, N, nbk, E, boffs, gcursor);

    // 2) two-phase node-exact CSR build
    binfill_kernel<<<(E + BF_CHUNK - 1) / BF_CHUNK, 256, 0, stream>>>(src, dst, E, nbk, gcursor, entries);
    bucket2csr_kernel<<<nbk, 256, 0, stream>>>(entries, boffs, nbk, offs, csr_src, N, E);

    // 3) h1s = bf16((x @ W1) * dinv)
    gemm_tile_kernel<128, 64, 64, true><<<(N + 63) / 64, 256, 0, stream>>>(x, W1, dinv, h1s, N);

    // 4) h2 = relu(dinv*(gather h1s) + b1)   (fp32)
    gather_bf16_kernel<64, true><<<(N * 64 + 255) / 256, 256, 0, stream>>>(h1s, dinv, offs, csr_src, b1, h2, N);

    // 5) h3s = bf16((h2 @ W2) * dinv)
    gemm_tile_kernel<64, 32, 128, true><<<(N + 127) / 128, 256, 0, stream>>>(h2, W2, dinv, h3s, N);

    // 6) out = dinv*(gather h3s) + b2   (fp32)
    gather_bf16_kernel<32, false><<<(N * 32 + 255) / 256, 256, 0, stream>>>(h3s, dinv, offs, csr_src, b2, out, N);
}

// Round 11
// 303.196 us; speedup vs baseline: 4.0926x; 1.0904x over previous
//
#include <hip/hip_runtime.h>

// GCN 2-layer. R11: BF_CHUNK 16384->4096 (98->391 blocks). R10's binfill was
// occupancy-starved (98 blocks on 256 CUs, occ 3.2%, VALU 0.8%, BW 220 GB/s).
// Run length drops 21->5 entries (write amp ~3x on 6.4MB = cheap); parallelism 4x.

#define NBKT(n) (((n) + 127) >> 7)

__device__ inline float bf2f(unsigned short u) {
    union { unsigned int i; float f; } v;
    v.i = ((unsigned int)u) << 16;
    return v.f;
}
__device__ inline unsigned short f2bf(float f) {
    union { float f; unsigned int i; } v;
    v.f = f;
    unsigned int u = v.i;
    return (unsigned short)((u + 0x7fff + ((u >> 16) & 1)) >> 16);  // RTN-even
}

// ---------------- degree ----------------
__global__ void deg_kernel(const int* __restrict__ dst, int E, int* __restrict__ deg) {
    int e = blockIdx.x * blockDim.x + threadIdx.x;
    if (e < E) atomicAdd(&deg[dst[e]], 1);
}

__global__ void dinv_kernel(const int* __restrict__ deg, float* __restrict__ dinv, int N) {
    int i = blockIdx.x * blockDim.x + threadIdx.x;
    if (i < N) dinv[i] = rsqrtf((float)deg[i] + 1.0f);  // +1 = self-loop
}

// ---------------- bucket offsets (R8 proven) ----------------
__global__ void bscan_kernel(const int* __restrict__ deg, int N, int nbk, int E,
                             int* __restrict__ boffs, int* __restrict__ gcursor) {
    __shared__ int s[1024];
    const int t = threadIdx.x;
    int sum = 0;
    if (t < nbk) {
        int base = t * 128;
        int lim = min(128, N - base);
        for (int i = 0; i < lim; ++i) sum += deg[base + i];
    }
    s[t] = sum;
    __syncthreads();
    for (int off = 1; off < 1024; off <<= 1) {
        int x = (t >= off) ? s[t - off] : 0;
        __syncthreads();
        s[t] += x;
        __syncthreads();
    }
    if (t < nbk) {
        int excl = s[t] - sum;
        boffs[t] = excl;
        gcursor[t] = excl;
    }
    if (t == 0) boffs[nbk] = E;
}

// ---------------- binfill (R8 proven, smaller chunk): entry = (src<<7)|(dst&127) -----
#define BF_CHUNK 4096
__global__ void __launch_bounds__(256) binfill_kernel(
        const int* __restrict__ src, const int* __restrict__ dst, int E, int nbk,
        int* __restrict__ gcursor, int* __restrict__ entries) {
    __shared__ int cnt[NBKT(100000)];
    __shared__ int gbase[NBKT(100000)];
    __shared__ int rank[NBKT(100000)];
    const int t = threadIdx.x;
    const int beg = blockIdx.x * BF_CHUNK;
    const int end = min(E, beg + BF_CHUNK);
    for (int b = t; b < nbk; b += 256) cnt[b] = 0;
    __syncthreads();
    for (int i = beg + t; i < end; i += 256) atomicAdd(&cnt[dst[i] >> 7], 1);
    __syncthreads();
    for (int b = t; b < nbk; b += 256) {
        int c = cnt[b];
        gbase[b] = c ? atomicAdd(&gcursor[b], c) : 0;
        rank[b] = 0;
    }
    __syncthreads();
    for (int i = beg + t; i < end; i += 256) {
        int d = dst[i];
        int b = d >> 7;
        int r = atomicAdd(&rank[b], 1);
        entries[gbase[b] + r] = (src[i] << 7) | (d & 127);
    }
}

// ---------------- bucket2csr (R9 proven) ----------------
__global__ void __launch_bounds__(256) bucket2csr_kernel(
        const int* __restrict__ entries, const int* __restrict__ boffs, int nbk,
        int* __restrict__ offs, int* __restrict__ csr_src, int N, int E) {
    __shared__ int cnt[128];
    __shared__ int s[128];
    __shared__ int rank[128];
    const int t = threadIdx.x;
    const int b = blockIdx.x;
    const int beg = boffs[b];
    const int end = boffs[b + 1];
    if (t < 128) { cnt[t] = 0; rank[t] = 0; }
    __syncthreads();
    for (int i = beg + t; i < end; i += 256) atomicAdd(&cnt[entries[i] & 127], 1);
    __syncthreads();
    if (t < 128) s[t] = cnt[t];
    __syncthreads();
    for (int off = 1; off < 128; off <<= 1) {
        int x = 0;
        if (t < 128 && t >= off) x = s[t - off];
        __syncthreads();
        if (t < 128) s[t] += x;
        __syncthreads();
    }
    const int node0 = b * 128;
    if (t < 128 && node0 + t < N) offs[node0 + t] = beg + s[t] - cnt[t];
    if (b == 0 && t == 0) offs[N] = E;
    __syncthreads();
    for (int i = beg + t; i < end; i += 256) {
        int e = entries[i];
        int d = e & 127;
        int r = atomicAdd(&rank[d], 1);
        csr_src[beg + s[d] - cnt[d] + r] = (int)((unsigned)e >> 7);
    }
}

// ---------------- LDS-tiled GEMM (R6 proven), bf16-out option ----------------
#define FMA4(ACC, AV, WV) \
    ACC.x += (AV) * (WV).x; ACC.y += (AV) * (WV).y; ACC.z += (AV) * (WV).z; ACC.w += (AV) * (WV).w;

template <int K, int C, int BR, bool BF16OUT>
__global__ void __launch_bounds__(256) gemm_tile_kernel(
        const float* __restrict__ A, const float* __restrict__ W,
        const float* __restrict__ dinv, void* __restrict__ outv, int N) {
    constexpr int F4R = K / 4;
    constexpr int CG = C / 4;
    static_assert(256 / CG * 4 == BR, "geometry");
    __shared__ float Wl[K * C];
    __shared__ float Al[BR * K];

    const int t = threadIdx.x;
    for (int i = t; i < K * C / 4; i += 256) ((float4*)Wl)[i] = ((const float4*)W)[i];
    const int row0 = blockIdx.x * BR;
    for (int i = t; i < BR * F4R; i += 256) {
        int r = i / F4R, k4 = i % F4R;
        float4 v = make_float4(0.f, 0.f, 0.f, 0.f);
        if (row0 + r < N) v = ((const float4*)(A + (size_t)(row0 + r) * K))[k4];
        *(float4*)(Al + r * K + k4 * 4) = v;
    }
    __syncthreads();

    const int c0 = (t % CG) * 4;
    const int r0 = (t / CG) * 4;
    const float* Ab = Al + r0 * K;

    float4 acc0 = {0, 0, 0, 0}, acc1 = {0, 0, 0, 0}, acc2 = {0, 0, 0, 0}, acc3 = {0, 0, 0, 0};

#pragma unroll 2
    for (int k4 = 0; k4 < K / 4; ++k4) {
        float4 a0 = *(const float4*)(Ab + 0 * K + k4 * 4);
        float4 a1 = *(const float4*)(Ab + 1 * K + k4 * 4);
        float4 a2 = *(const float4*)(Ab + 2 * K + k4 * 4);
        float4 a3 = *(const float4*)(Ab + 3 * K + k4 * 4);
        float4 w0 = *(const float4*)(Wl + (k4 * 4 + 0) * C + c0);
        float4 w1 = *(const float4*)(Wl + (k4 * 4 + 1) * C + c0);
        float4 w2 = *(const float4*)(Wl + (k4 * 4 + 2) * C + c0);
        float4 w3 = *(const float4*)(Wl + (k4 * 4 + 3) * C + c0);
        FMA4(acc0, a0.x, w0) FMA4(acc1, a1.x, w0) FMA4(acc2, a2.x, w0) FMA4(acc3, a3.x, w0)
        FMA4(acc0, a0.y, w1) FMA4(acc1, a1.y, w1) FMA4(acc2, a2.y, w1) FMA4(acc3, a3.y, w1)
        FMA4(acc0, a0.z, w2) FMA4(acc1, a1.z, w2) FMA4(acc2, a2.z, w2) FMA4(acc3, a3.z, w2)
        FMA4(acc0, a0.w, w3) FMA4(acc1, a1.w, w3) FMA4(acc2, a2.w, w3) FMA4(acc3, a3.w, w3)
    }

    const int row = row0 + r0;
#pragma unroll
    for (int i = 0; i < 4; ++i) {
        int rr = row + i;
        if (rr < N) {
            float d = dinv[rr];
            float4 fr = (i == 0) ? acc0 : (i == 1) ? acc1 : (i == 2) ? acc2 : acc3;
            fr.x *= d; fr.y *= d; fr.z *= d; fr.w *= d;
            if (BF16OUT) {
                ushort4 o;
                o.x = f2bf(fr.x); o.y = f2bf(fr.y); o.z = f2bf(fr.z); o.w = f2bf(fr.w);
                *(ushort4*)((unsigned short*)outv + (size_t)rr * C + c0) = o;
            } else {
                *(float4*)((float*)outv + (size_t)rr * C + c0) = fr;
            }
        }
    }
}

// ---------------- per-node gather from bf16 table (R10 proven) ----------------
template <int C, bool RELU>
__global__ void gather_bf16_kernel(
        const unsigned short* __restrict__ hs, const float* __restrict__ dinv,
        const int* __restrict__ offs, const int* __restrict__ csr_src,
        const float* __restrict__ b, float* __restrict__ out, int N) {
    int gtid = blockIdx.x * blockDim.x + threadIdx.x;
    int lane = gtid % C;
    int d = gtid / C;
    if (d >= N) return;
    float acc = bf2f(hs[(size_t)d * C + lane]);  // self-loop term
    int beg = offs[d];
    int end = offs[d + 1];
    int j = beg;
    for (; j + 3 < end; j += 4) {
        int s0 = csr_src[j];
        int s1 = csr_src[j + 1];
        int s2 = csr_src[j + 2];
        int s3 = csr_src[j + 3];
        float v0 = bf2f(hs[(size_t)s0 * C + lane]);
        float v1 = bf2f(hs[(size_t)s1 * C + lane]);
        float v2 = bf2f(hs[(size_t)s2 * C + lane]);
        float v3 = bf2f(hs[(size_t)s3 * C + lane]);
        acc += v0 + v1 + v2 + v3;
    }
    for (; j < end; ++j) acc += bf2f(hs[(size_t)csr_src[j] * C + lane]);
    float r = acc * dinv[d] + b[lane];
    if (RELU) r = fmaxf(r, 0.f);
    out[(size_t)d * C + lane] = r;
}

extern "C" void kernel_launch(void* const* d_in, const int* in_sizes, int n_in,
                              void* d_out, int out_size, void* d_ws, size_t ws_size,
                              hipStream_t stream) {
    const float* x = (const float*)d_in[0];
    const int* ei = (const int*)d_in[1];
    const float* W1 = (const float*)d_in[2];
    const float* b1 = (const float*)d_in[3];
    const float* W2 = (const float*)d_in[4];
    const float* b2 = (const float*)d_in[5];

    const int N = in_sizes[0] / 128;  // 100000
    const int E = in_sizes[1] / 2;    // 1600000
    const int* src = ei;
    const int* dst = ei + E;
    const int nbk = NBKT(N);          // 782 buckets of 128 dst nodes

    // workspace layout (4-byte units unless noted)
    int* deg = (int*)d_ws;                             // N
    float* dinv = (float*)(deg + ((N + 255) & ~255));  // N
    int* boffs = (int*)(dinv + ((N + 255) & ~255));    // nbk+1 (pad 1024)
    int* gcursor = boffs + 1024;                       // nbk (pad 1024)
    int* offs = gcursor + 1024;                        // N+1
    int* entries = offs + ((N + 1 + 255) & ~255);      // E
    int* csr_src = entries + ((E + 255) & ~255);       // E
    unsigned short* h1s = (unsigned short*)(csr_src + ((E + 255) & ~255));  // N*64 bf16
    float* h2 = (float*)(h1s + (size_t)N * 64);        // N*64 fp32
    unsigned short* h3s = h1s;                         // reuse (N*32 bf16)
    float* out = (float*)d_out;

    // 1) degrees -> dinv ; bucket offsets
    hipMemsetAsync(deg, 0, (size_t)N * 4, stream);
    deg_kernel<<<(E + 255) / 256, 256, 0, stream>>>(dst, E, deg);
    dinv_kernel<<<(N + 255) / 256, 256, 0, stream>>>(deg, dinv, N);
    bscan_kernel<<<1, 1024, 0, stream>>>(deg, N, nbk, E, boffs, gcursor);

    // 2) two-phase node-exact CSR build
    binfill_kernel<<<(E + BF_CHUNK - 1) / BF_CHUNK, 256, 0, stream>>>(src, dst, E, nbk, gcursor, entries);
    bucket2csr_kernel<<<nbk, 256, 0, stream>>>(entries, boffs, nbk, offs, csr_src, N, E);

    // 3) h1s = bf16((x @ W1) * dinv)
    gemm_tile_kernel<128, 64, 64, true><<<(N + 63) / 64, 256, 0, stream>>>(x, W1, dinv, h1s, N);

    // 4) h2 = relu(dinv*(gather h1s) + b1)   (fp32)
    gather_bf16_kernel<64, true><<<(N * 64 + 255) / 256, 256, 0, stream>>>(h1s, dinv, offs, csr_src, b1, h2, N);

    // 5) h3s = bf16((h2 @ W2) * dinv)
    gemm_tile_kernel<64, 32, 128, true><<<(N + 127) / 128, 256, 0, stream>>>(h2, W2, dinv, h3s, N);

    // 6) out = dinv*(gather h3s) + b2   (fp32)
    gather_bf16_kernel<32, false><<<(N * 32 + 255) / 256, 256, 0, stream>>>(h3s, dinv, offs, csr_src, b2, out, N);
}

// Round 12
// 284.876 us; speedup vs baseline: 4.3558x; 1.0643x over previous
//
#include <hip/hip_runtime.h>

// GCN 2-layer. R12: gathers rebuilt for MLP -- wave-uniform node (C=64) so indices
// ride the scalar path, 8-wide edge unroll with 4 independent accumulators.
// R11 gather was latency-bound: VALU 35%, eff BW 1.3TB/s, fetch at per-XCD
// compulsory floor (88MB) -- traffic can't drop, depth can rise.

#define NBKT(n) (((n) + 127) >> 7)

__device__ inline float bf2f(unsigned short u) {
    union { unsigned int i; float f; } v;
    v.i = ((unsigned int)u) << 16;
    return v.f;
}
__device__ inline unsigned short f2bf(float f) {
    union { float f; unsigned int i; } v;
    v.f = f;
    unsigned int u = v.i;
    return (unsigned short)((u + 0x7fff + ((u >> 16) & 1)) >> 16);  // RTN-even
}

// ---------------- degree ----------------
__global__ void deg_kernel(const int* __restrict__ dst, int E, int* __restrict__ deg) {
    int e = blockIdx.x * blockDim.x + threadIdx.x;
    if (e < E) atomicAdd(&deg[dst[e]], 1);
}

__global__ void dinv_kernel(const int* __restrict__ deg, float* __restrict__ dinv, int N) {
    int i = blockIdx.x * blockDim.x + threadIdx.x;
    if (i < N) dinv[i] = rsqrtf((float)deg[i] + 1.0f);  // +1 = self-loop
}

// ---------------- bucket offsets (R8 proven) ----------------
__global__ void bscan_kernel(const int* __restrict__ deg, int N, int nbk, int E,
                             int* __restrict__ boffs, int* __restrict__ gcursor) {
    __shared__ int s[1024];
    const int t = threadIdx.x;
    int sum = 0;
    if (t < nbk) {
        int base = t * 128;
        int lim = min(128, N - base);
        for (int i = 0; i < lim; ++i) sum += deg[base + i];
    }
    s[t] = sum;
    __syncthreads();
    for (int off = 1; off < 1024; off <<= 1) {
        int x = (t >= off) ? s[t - off] : 0;
        __syncthreads();
        s[t] += x;
        __syncthreads();
    }
    if (t < nbk) {
        int excl = s[t] - sum;
        boffs[t] = excl;
        gcursor[t] = excl;
    }
    if (t == 0) boffs[nbk] = E;
}

// ---------------- binfill (R8/R11 proven): entry = (src<<7)|(dst&127) ----------------
#define BF_CHUNK 4096
__global__ void __launch_bounds__(256) binfill_kernel(
        const int* __restrict__ src, const int* __restrict__ dst, int E, int nbk,
        int* __restrict__ gcursor, int* __restrict__ entries) {
    __shared__ int cnt[NBKT(100000)];
    __shared__ int gbase[NBKT(100000)];
    __shared__ int rank[NBKT(100000)];
    const int t = threadIdx.x;
    const int beg = blockIdx.x * BF_CHUNK;
    const int end = min(E, beg + BF_CHUNK);
    for (int b = t; b < nbk; b += 256) cnt[b] = 0;
    __syncthreads();
    for (int i = beg + t; i < end; i += 256) atomicAdd(&cnt[dst[i] >> 7], 1);
    __syncthreads();
    for (int b = t; b < nbk; b += 256) {
        int c = cnt[b];
        gbase[b] = c ? atomicAdd(&gcursor[b], c) : 0;
        rank[b] = 0;
    }
    __syncthreads();
    for (int i = beg + t; i < end; i += 256) {
        int d = dst[i];
        int b = d >> 7;
        int r = atomicAdd(&rank[b], 1);
        entries[gbase[b] + r] = (src[i] << 7) | (d & 127);
    }
}

// ---------------- bucket2csr (R9 proven) ----------------
__global__ void __launch_bounds__(256) bucket2csr_kernel(
        const int* __restrict__ entries, const int* __restrict__ boffs, int nbk,
        int* __restrict__ offs, int* __restrict__ csr_src, int N, int E) {
    __shared__ int cnt[128];
    __shared__ int s[128];
    __shared__ int rank[128];
    const int t = threadIdx.x;
    const int b = blockIdx.x;
    const int beg = boffs[b];
    const int end = boffs[b + 1];
    if (t < 128) { cnt[t] = 0; rank[t] = 0; }
    __syncthreads();
    for (int i = beg + t; i < end; i += 256) atomicAdd(&cnt[entries[i] & 127], 1);
    __syncthreads();
    if (t < 128) s[t] = cnt[t];
    __syncthreads();
    for (int off = 1; off < 128; off <<= 1) {
        int x = 0;
        if (t < 128 && t >= off) x = s[t - off];
        __syncthreads();
        if (t < 128) s[t] += x;
        __syncthreads();
    }
    const int node0 = b * 128;
    if (t < 128 && node0 + t < N) offs[node0 + t] = beg + s[t] - cnt[t];
    if (b == 0 && t == 0) offs[N] = E;
    __syncthreads();
    for (int i = beg + t; i < end; i += 256) {
        int e = entries[i];
        int d = e & 127;
        int r = atomicAdd(&rank[d], 1);
        csr_src[beg + s[d] - cnt[d] + r] = (int)((unsigned)e >> 7);
    }
}

// ---------------- LDS-tiled GEMM (R6 proven), bf16-out option ----------------
#define FMA4(ACC, AV, WV) \
    ACC.x += (AV) * (WV).x; ACC.y += (AV) * (WV).y; ACC.z += (AV) * (WV).z; ACC.w += (AV) * (WV).w;

template <int K, int C, int BR, bool BF16OUT>
__global__ void __launch_bounds__(256) gemm_tile_kernel(
        const float* __restrict__ A, const float* __restrict__ W,
        const float* __restrict__ dinv, void* __restrict__ outv, int N) {
    constexpr int F4R = K / 4;
    constexpr int CG = C / 4;
    static_assert(256 / CG * 4 == BR, "geometry");
    __shared__ float Wl[K * C];
    __shared__ float Al[BR * K];

    const int t = threadIdx.x;
    for (int i = t; i < K * C / 4; i += 256) ((float4*)Wl)[i] = ((const float4*)W)[i];
    const int row0 = blockIdx.x * BR;
    for (int i = t; i < BR * F4R; i += 256) {
        int r = i / F4R, k4 = i % F4R;
        float4 v = make_float4(0.f, 0.f, 0.f, 0.f);
        if (row0 + r < N) v = ((const float4*)(A + (size_t)(row0 + r) * K))[k4];
        *(float4*)(Al + r * K + k4 * 4) = v;
    }
    __syncthreads();

    const int c0 = (t % CG) * 4;
    const int r0 = (t / CG) * 4;
    const float* Ab = Al + r0 * K;

    float4 acc0 = {0, 0, 0, 0}, acc1 = {0, 0, 0, 0}, acc2 = {0, 0, 0, 0}, acc3 = {0, 0, 0, 0};

#pragma unroll 2
    for (int k4 = 0; k4 < K / 4; ++k4) {
        float4 a0 = *(const float4*)(Ab + 0 * K + k4 * 4);
        float4 a1 = *(const float4*)(Ab + 1 * K + k4 * 4);
        float4 a2 = *(const float4*)(Ab + 2 * K + k4 * 4);
        float4 a3 = *(const float4*)(Ab + 3 * K + k4 * 4);
        float4 w0 = *(const float4*)(Wl + (k4 * 4 + 0) * C + c0);
        float4 w1 = *(const float4*)(Wl + (k4 * 4 + 1) * C + c0);
        float4 w2 = *(const float4*)(Wl + (k4 * 4 + 2) * C + c0);
        float4 w3 = *(const float4*)(Wl + (k4 * 4 + 3) * C + c0);
        FMA4(acc0, a0.x, w0) FMA4(acc1, a1.x, w0) FMA4(acc2, a2.x, w0) FMA4(acc3, a3.x, w0)
        FMA4(acc0, a0.y, w1) FMA4(acc1, a1.y, w1) FMA4(acc2, a2.y, w1) FMA4(acc3, a3.y, w1)
        FMA4(acc0, a0.z, w2) FMA4(acc1, a1.z, w2) FMA4(acc2, a2.z, w2) FMA4(acc3, a3.z, w2)
        FMA4(acc0, a0.w, w3) FMA4(acc1, a1.w, w3) FMA4(acc2, a2.w, w3) FMA4(acc3, a3.w, w3)
    }

    const int row = row0 + r0;
#pragma unroll
    for (int i = 0; i < 4; ++i) {
        int rr = row + i;
        if (rr < N) {
            float d = dinv[rr];
            float4 fr = (i == 0) ? acc0 : (i == 1) ? acc1 : (i == 2) ? acc2 : acc3;
            fr.x *= d; fr.y *= d; fr.z *= d; fr.w *= d;
            if (BF16OUT) {
                ushort4 o;
                o.x = f2bf(fr.x); o.y = f2bf(fr.y); o.z = f2bf(fr.z); o.w = f2bf(fr.w);
                *(ushort4*)((unsigned short*)outv + (size_t)rr * C + c0) = o;
            } else {
                *(float4*)((float*)outv + (size_t)rr * C + c0) = fr;
            }
        }
    }
}

// ---------------- gather C=64: one node per wave (uniform indices), 8-wide MLP -------
template <bool RELU>
__global__ void __launch_bounds__(256) gather64_kernel(
        const unsigned short* __restrict__ hs, const float* __restrict__ dinv,
        const int* __restrict__ offs, const int* __restrict__ csr_src,
        const float* __restrict__ b, float* __restrict__ out, int N) {
    const int lane = threadIdx.x & 63;
    const int d = blockIdx.x * 4 + (threadIdx.x >> 6);  // wave-uniform
    if (d >= N) return;
    const int beg = offs[d];
    const int end = offs[d + 1];
    float acc0 = bf2f(hs[(size_t)d * 64 + lane]);  // self-loop
    float acc1 = 0.f, acc2 = 0.f, acc3 = 0.f;
    int j = beg;
    for (; j + 7 < end; j += 8) {
        int s0 = csr_src[j + 0], s1 = csr_src[j + 1], s2 = csr_src[j + 2], s3 = csr_src[j + 3];
        int s4 = csr_src[j + 4], s5 = csr_src[j + 5], s6 = csr_src[j + 6], s7 = csr_src[j + 7];
        float v0 = bf2f(hs[(size_t)s0 * 64 + lane]);
        float v1 = bf2f(hs[(size_t)s1 * 64 + lane]);
        float v2 = bf2f(hs[(size_t)s2 * 64 + lane]);
        float v3 = bf2f(hs[(size_t)s3 * 64 + lane]);
        float v4 = bf2f(hs[(size_t)s4 * 64 + lane]);
        float v5 = bf2f(hs[(size_t)s5 * 64 + lane]);
        float v6 = bf2f(hs[(size_t)s6 * 64 + lane]);
        float v7 = bf2f(hs[(size_t)s7 * 64 + lane]);
        acc0 += v0; acc1 += v1; acc2 += v2; acc3 += v3;
        acc0 += v4; acc1 += v5; acc2 += v6; acc3 += v7;
    }
    if (j + 3 < end) {
        int s0 = csr_src[j + 0], s1 = csr_src[j + 1], s2 = csr_src[j + 2], s3 = csr_src[j + 3];
        acc0 += bf2f(hs[(size_t)s0 * 64 + lane]);
        acc1 += bf2f(hs[(size_t)s1 * 64 + lane]);
        acc2 += bf2f(hs[(size_t)s2 * 64 + lane]);
        acc3 += bf2f(hs[(size_t)s3 * 64 + lane]);
        j += 4;
    }
    for (; j < end; ++j) acc0 += bf2f(hs[(size_t)csr_src[j] * 64 + lane]);
    float r = ((acc0 + acc1) + (acc2 + acc3)) * dinv[d] + b[lane];
    if (RELU) r = fmaxf(r, 0.f);
    out[(size_t)d * 64 + lane] = r;
}

// ---------------- gather C=32: 2 nodes per wave, 8-wide MLP ----------------
__global__ void __launch_bounds__(256) gather32_kernel(
        const unsigned short* __restrict__ hs, const float* __restrict__ dinv,
        const int* __restrict__ offs, const int* __restrict__ csr_src,
        const float* __restrict__ b, float* __restrict__ out, int N) {
    const int lane = threadIdx.x & 31;
    const int d = blockIdx.x * 8 + (threadIdx.x >> 5);
    if (d >= N) return;
    const int beg = offs[d];
    const int end = offs[d + 1];
    float acc0 = bf2f(hs[(size_t)d * 32 + lane]);  // self-loop
    float acc1 = 0.f, acc2 = 0.f, acc3 = 0.f;
    int j = beg;
    for (; j + 7 < end; j += 8) {
        int s0 = csr_src[j + 0], s1 = csr_src[j + 1], s2 = csr_src[j + 2], s3 = csr_src[j + 3];
        int s4 = csr_src[j + 4], s5 = csr_src[j + 5], s6 = csr_src[j + 6], s7 = csr_src[j + 7];
        float v0 = bf2f(hs[(size_t)s0 * 32 + lane]);
        float v1 = bf2f(hs[(size_t)s1 * 32 + lane]);
        float v2 = bf2f(hs[(size_t)s2 * 32 + lane]);
        float v3 = bf2f(hs[(size_t)s3 * 32 + lane]);
        float v4 = bf2f(hs[(size_t)s4 * 32 + lane]);
        float v5 = bf2f(hs[(size_t)s5 * 32 + lane]);
        float v6 = bf2f(hs[(size_t)s6 * 32 + lane]);
        float v7 = bf2f(hs[(size_t)s7 * 32 + lane]);
        acc0 += v0; acc1 += v1; acc2 += v2; acc3 += v3;
        acc0 += v4; acc1 += v5; acc2 += v6; acc3 += v7;
    }
    if (j + 3 < end) {
        int s0 = csr_src[j + 0], s1 = csr_src[j + 1], s2 = csr_src[j + 2], s3 = csr_src[j + 3];
        acc0 += bf2f(hs[(size_t)s0 * 32 + lane]);
        acc1 += bf2f(hs[(size_t)s1 * 32 + lane]);
        acc2 += bf2f(hs[(size_t)s2 * 32 + lane]);
        acc3 += bf2f(hs[(size_t)s3 * 32 + lane]);
        j += 4;
    }
    for (; j < end; ++j) acc0 += bf2f(hs[(size_t)csr_src[j] * 32 + lane]);
    float r = ((acc0 + acc1) + (acc2 + acc3)) * dinv[d] + b[lane];
    out[(size_t)d * 32 + lane] = r;
}

extern "C" void kernel_launch(void* const* d_in, const int* in_sizes, int n_in,
                              void* d_out, int out_size, void* d_ws, size_t ws_size,
                              hipStream_t stream) {
    const float* x = (const float*)d_in[0];
    const int* ei = (const int*)d_in[1];
    const float* W1 = (const float*)d_in[2];
    const float* b1 = (const float*)d_in[3];
    const float* W2 = (const float*)d_in[4];
    const float* b2 = (const float*)d_in[5];

    const int N = in_sizes[0] / 128;  // 100000
    const int E = in_sizes[1] / 2;    // 1600000
    const int* src = ei;
    const int* dst = ei + E;
    const int nbk = NBKT(N);          // 782 buckets of 128 dst nodes

    // workspace layout (4-byte units unless noted)
    int* deg = (int*)d_ws;                             // N
    float* dinv = (float*)(deg + ((N + 255) & ~255));  // N
    int* boffs = (int*)(dinv + ((N + 255) & ~255));    // nbk+1 (pad 1024)
    int* gcursor = boffs + 1024;                       // nbk (pad 1024)
    int* offs = gcursor + 1024;                        // N+1
    int* entries = offs + ((N + 1 + 255) & ~255);      // E
    int* csr_src = entries + ((E + 255) & ~255);       // E
    unsigned short* h1s = (unsigned short*)(csr_src + ((E + 255) & ~255));  // N*64 bf16
    float* h2 = (float*)(h1s + (size_t)N * 64);        // N*64 fp32
    unsigned short* h3s = h1s;                         // reuse (N*32 bf16)
    float* out = (float*)d_out;

    // 1) degrees -> dinv ; bucket offsets
    hipMemsetAsync(deg, 0, (size_t)N * 4, stream);
    deg_kernel<<<(E + 255) / 256, 256, 0, stream>>>(dst, E, deg);
    dinv_kernel<<<(N + 255) / 256, 256, 0, stream>>>(deg, dinv, N);
    bscan_kernel<<<1, 1024, 0, stream>>>(deg, N, nbk, E, boffs, gcursor);

    // 2) two-phase node-exact CSR build
    binfill_kernel<<<(E + BF_CHUNK - 1) / BF_CHUNK, 256, 0, stream>>>(src, dst, E, nbk, gcursor, entries);
    bucket2csr_kernel<<<nbk, 256, 0, stream>>>(entries, boffs, nbk, offs, csr_src, N, E);

    // 3) h1s = bf16((x @ W1) * dinv)
    gemm_tile_kernel<128, 64, 64, true><<<(N + 63) / 64, 256, 0, stream>>>(x, W1, dinv, h1s, N);

    // 4) h2 = relu(dinv*(gather h1s) + b1)   (fp32)
    gather64_kernel<true><<<(N + 3) / 4, 256, 0, stream>>>(h1s, dinv, offs, csr_src, b1, h2, N);

    // 5) h3s = bf16((h2 @ W2) * dinv)
    gemm_tile_kernel<64, 32, 128, true><<<(N + 127) / 128, 256, 0, stream>>>(h2, W2, dinv, h3s, N);

    // 6) out = dinv*(gather h3s) + b2   (fp32)
    gather32_kernel<<<(N + 7) / 8, 256, 0, stream>>>(h3s, dinv, offs, csr_src, b2, out, N);
}

// Round 13
// 204.994 us; speedup vs baseline: 6.0531x; 1.3897x over previous
//
#include <hip/hip_runtime.h>

// GCN 2-layer. R13: kill deg_kernel (65us, 50MB write-through for a 400KB histogram).
// Bucket counts now come from an LDS-privatized bucket histogram (bhist, 782 counters);
// node-exact degrees fall out of bucket2csr's existing LDS cnt[] -> dinv written there.

#define NBKT(n) (((n) + 127) >> 7)

__device__ inline float bf2f(unsigned short u) {
    union { unsigned int i; float f; } v;
    v.i = ((unsigned int)u) << 16;
    return v.f;
}
__device__ inline unsigned short f2bf(float f) {
    union { float f; unsigned int i; } v;
    v.f = f;
    unsigned int u = v.i;
    return (unsigned short)((u + 0x7fff + ((u >> 16) & 1)) >> 16);  // RTN-even
}

// ---------------- bucket histogram: bcnt[b] = #edges with dst in bucket b ------------
#define BH_CHUNK 4096
__global__ void __launch_bounds__(256) bhist_kernel(
        const int* __restrict__ dst, int E, int nbk, int* __restrict__ bcnt) {
    __shared__ int cnt[NBKT(100000)];
    const int t = threadIdx.x;
    const int beg = blockIdx.x * BH_CHUNK;
    const int end = min(E, beg + BH_CHUNK);
    for (int b = t; b < nbk; b += 256) cnt[b] = 0;
    __syncthreads();
    for (int i = beg + t; i < end; i += 256) atomicAdd(&cnt[dst[i] >> 7], 1);
    __syncthreads();
    for (int b = t; b < nbk; b += 256) {
        int c = cnt[b];
        if (c) atomicAdd(&bcnt[b], c);  // 3KB array, L2-resident
    }
}

// ---------------- bucket offsets: boffs = exscan(bcnt) ----------------
__global__ void bscan_kernel(const int* __restrict__ bcnt, int nbk, int E,
                             int* __restrict__ boffs, int* __restrict__ gcursor) {
    __shared__ int s[1024];
    const int t = threadIdx.x;
    int v = (t < nbk) ? bcnt[t] : 0;
    s[t] = v;
    __syncthreads();
    for (int off = 1; off < 1024; off <<= 1) {
        int x = (t >= off) ? s[t - off] : 0;
        __syncthreads();
        s[t] += x;
        __syncthreads();
    }
    if (t < nbk) {
        int excl = s[t] - v;
        boffs[t] = excl;
        gcursor[t] = excl;
    }
    if (t == 0) boffs[nbk] = E;
}

// ---------------- binfill (R8/R11 proven): entry = (src<<7)|(dst&127) ----------------
#define BF_CHUNK 4096
__global__ void __launch_bounds__(256) binfill_kernel(
        const int* __restrict__ src, const int* __restrict__ dst, int E, int nbk,
        int* __restrict__ gcursor, int* __restrict__ entries) {
    __shared__ int cnt[NBKT(100000)];
    __shared__ int gbase[NBKT(100000)];
    __shared__ int rank[NBKT(100000)];
    const int t = threadIdx.x;
    const int beg = blockIdx.x * BF_CHUNK;
    const int end = min(E, beg + BF_CHUNK);
    for (int b = t; b < nbk; b += 256) cnt[b] = 0;
    __syncthreads();
    for (int i = beg + t; i < end; i += 256) atomicAdd(&cnt[dst[i] >> 7], 1);
    __syncthreads();
    for (int b = t; b < nbk; b += 256) {
        int c = cnt[b];
        gbase[b] = c ? atomicAdd(&gcursor[b], c) : 0;
        rank[b] = 0;
    }
    __syncthreads();
    for (int i = beg + t; i < end; i += 256) {
        int d = dst[i];
        int b = d >> 7;
        int r = atomicAdd(&rank[b], 1);
        entries[gbase[b] + r] = (src[i] << 7) | (d & 127);
    }
}

// ---------------- bucket2csr (R9 proven) + dinv emission ----------------
__global__ void __launch_bounds__(256) bucket2csr_kernel(
        const int* __restrict__ entries, const int* __restrict__ boffs, int nbk,
        int* __restrict__ offs, int* __restrict__ csr_src, float* __restrict__ dinv,
        int N, int E) {
    __shared__ int cnt[128];
    __shared__ int s[128];
    __shared__ int rank[128];
    const int t = threadIdx.x;
    const int b = blockIdx.x;
    const int beg = boffs[b];
    const int end = boffs[b + 1];
    if (t < 128) { cnt[t] = 0; rank[t] = 0; }
    __syncthreads();
    for (int i = beg + t; i < end; i += 256) atomicAdd(&cnt[entries[i] & 127], 1);
    __syncthreads();
    if (t < 128) s[t] = cnt[t];
    __syncthreads();
    for (int off = 1; off < 128; off <<= 1) {
        int x = 0;
        if (t < 128 && t >= off) x = s[t - off];
        __syncthreads();
        if (t < 128) s[t] += x;
        __syncthreads();
    }
    const int node0 = b * 128;
    if (t < 128 && node0 + t < N) {
        offs[node0 + t] = beg + s[t] - cnt[t];
        dinv[node0 + t] = rsqrtf((float)cnt[t] + 1.0f);  // +1 = self-loop
    }
    if (b == 0 && t == 0) offs[N] = E;
    __syncthreads();
    for (int i = beg + t; i < end; i += 256) {
        int e = entries[i];
        int d = e & 127;
        int r = atomicAdd(&rank[d], 1);
        csr_src[beg + s[d] - cnt[d] + r] = (int)((unsigned)e >> 7);
    }
}

// ---------------- LDS-tiled GEMM (R6 proven), bf16-out option ----------------
#define FMA4(ACC, AV, WV) \
    ACC.x += (AV) * (WV).x; ACC.y += (AV) * (WV).y; ACC.z += (AV) * (WV).z; ACC.w += (AV) * (WV).w;

template <int K, int C, int BR, bool BF16OUT>
__global__ void __launch_bounds__(256) gemm_tile_kernel(
        const float* __restrict__ A, const float* __restrict__ W,
        const float* __restrict__ dinv, void* __restrict__ outv, int N) {
    constexpr int F4R = K / 4;
    constexpr int CG = C / 4;
    static_assert(256 / CG * 4 == BR, "geometry");
    __shared__ float Wl[K * C];
    __shared__ float Al[BR * K];

    const int t = threadIdx.x;
    for (int i = t; i < K * C / 4; i += 256) ((float4*)Wl)[i] = ((const float4*)W)[i];
    const int row0 = blockIdx.x * BR;
    for (int i = t; i < BR * F4R; i += 256) {
        int r = i / F4R, k4 = i % F4R;
        float4 v = make_float4(0.f, 0.f, 0.f, 0.f);
        if (row0 + r < N) v = ((const float4*)(A + (size_t)(row0 + r) * K))[k4];
        *(float4*)(Al + r * K + k4 * 4) = v;
    }
    __syncthreads();

    const int c0 = (t % CG) * 4;
    const int r0 = (t / CG) * 4;
    const float* Ab = Al + r0 * K;

    float4 acc0 = {0, 0, 0, 0}, acc1 = {0, 0, 0, 0}, acc2 = {0, 0, 0, 0}, acc3 = {0, 0, 0, 0};

#pragma unroll 2
    for (int k4 = 0; k4 < K / 4; ++k4) {
        float4 a0 = *(const float4*)(Ab + 0 * K + k4 * 4);
        float4 a1 = *(const float4*)(Ab + 1 * K + k4 * 4);
        float4 a2 = *(const float4*)(Ab + 2 * K + k4 * 4);
        float4 a3 = *(const float4*)(Ab + 3 * K + k4 * 4);
        float4 w0 = *(const float4*)(Wl + (k4 * 4 + 0) * C + c0);
        float4 w1 = *(const float4*)(Wl + (k4 * 4 + 1) * C + c0);
        float4 w2 = *(const float4*)(Wl + (k4 * 4 + 2) * C + c0);
        float4 w3 = *(const float4*)(Wl + (k4 * 4 + 3) * C + c0);
        FMA4(acc0, a0.x, w0) FMA4(acc1, a1.x, w0) FMA4(acc2, a2.x, w0) FMA4(acc3, a3.x, w0)
        FMA4(acc0, a0.y, w1) FMA4(acc1, a1.y, w1) FMA4(acc2, a2.y, w1) FMA4(acc3, a3.y, w1)
        FMA4(acc0, a0.z, w2) FMA4(acc1, a1.z, w2) FMA4(acc2, a2.z, w2) FMA4(acc3, a3.z, w2)
        FMA4(acc0, a0.w, w3) FMA4(acc1, a1.w, w3) FMA4(acc2, a2.w, w3) FMA4(acc3, a3.w, w3)
    }

    const int row = row0 + r0;
#pragma unroll
    for (int i = 0; i < 4; ++i) {
        int rr = row + i;
        if (rr < N) {
            float d = dinv[rr];
            float4 fr = (i == 0) ? acc0 : (i == 1) ? acc1 : (i == 2) ? acc2 : acc3;
            fr.x *= d; fr.y *= d; fr.z *= d; fr.w *= d;
            if (BF16OUT) {
                ushort4 o;
                o.x = f2bf(fr.x); o.y = f2bf(fr.y); o.z = f2bf(fr.z); o.w = f2bf(fr.w);
                *(ushort4*)((unsigned short*)outv + (size_t)rr * C + c0) = o;
            } else {
                *(float4*)((float*)outv + (size_t)rr * C + c0) = fr;
            }
        }
    }
}

// ---------------- gather C=64 (R12 proven): one node/wave, 8-wide MLP ----------------
template <bool RELU>
__global__ void __launch_bounds__(256) gather64_kernel(
        const unsigned short* __restrict__ hs, const float* __restrict__ dinv,
        const int* __restrict__ offs, const int* __restrict__ csr_src,
        const float* __restrict__ b, float* __restrict__ out, int N) {
    const int lane = threadIdx.x & 63;
    const int d = blockIdx.x * 4 + (threadIdx.x >> 6);  // wave-uniform
    if (d >= N) return;
    const int beg = offs[d];
    const int end = offs[d + 1];
    float acc0 = bf2f(hs[(size_t)d * 64 + lane]);  // self-loop
    float acc1 = 0.f, acc2 = 0.f, acc3 = 0.f;
    int j = beg;
    for (; j + 7 < end; j += 8) {
        int s0 = csr_src[j + 0], s1 = csr_src[j + 1], s2 = csr_src[j + 2], s3 = csr_src[j + 3];
        int s4 = csr_src[j + 4], s5 = csr_src[j + 5], s6 = csr_src[j + 6], s7 = csr_src[j + 7];
        float v0 = bf2f(hs[(size_t)s0 * 64 + lane]);
        float v1 = bf2f(hs[(size_t)s1 * 64 + lane]);
        float v2 = bf2f(hs[(size_t)s2 * 64 + lane]);
        float v3 = bf2f(hs[(size_t)s3 * 64 + lane]);
        float v4 = bf2f(hs[(size_t)s4 * 64 + lane]);
        float v5 = bf2f(hs[(size_t)s5 * 64 + lane]);
        float v6 = bf2f(hs[(size_t)s6 * 64 + lane]);
        float v7 = bf2f(hs[(size_t)s7 * 64 + lane]);
        acc0 += v0; acc1 += v1; acc2 += v2; acc3 += v3;
        acc0 += v4; acc1 += v5; acc2 += v6; acc3 += v7;
    }
    if (j + 3 < end) {
        int s0 = csr_src[j + 0], s1 = csr_src[j + 1], s2 = csr_src[j + 2], s3 = csr_src[j + 3];
        acc0 += bf2f(hs[(size_t)s0 * 64 + lane]);
        acc1 += bf2f(hs[(size_t)s1 * 64 + lane]);
        acc2 += bf2f(hs[(size_t)s2 * 64 + lane]);
        acc3 += bf2f(hs[(size_t)s3 * 64 + lane]);
        j += 4;
    }
    for (; j < end; ++j) acc0 += bf2f(hs[(size_t)csr_src[j] * 64 + lane]);
    float r = ((acc0 + acc1) + (acc2 + acc3)) * dinv[d] + b[lane];
    if (RELU) r = fmaxf(r, 0.f);
    out[(size_t)d * 64 + lane] = r;
}

// ---------------- gather C=32 (R12 proven): 2 nodes/wave, 8-wide MLP ----------------
__global__ void __launch_bounds__(256) gather32_kernel(
        const unsigned short* __restrict__ hs, const float* __restrict__ dinv,
        const int* __restrict__ offs, const int* __restrict__ csr_src,
        const float* __restrict__ b, float* __restrict__ out, int N) {
    const int lane = threadIdx.x & 31;
    const int d = blockIdx.x * 8 + (threadIdx.x >> 5);
    if (d >= N) return;
    const int beg = offs[d];
    const int end = offs[d + 1];
    float acc0 = bf2f(hs[(size_t)d * 32 + lane]);  // self-loop
    float acc1 = 0.f, acc2 = 0.f, acc3 = 0.f;
    int j = beg;
    for (; j + 7 < end; j += 8) {
        int s0 = csr_src[j + 0], s1 = csr_src[j + 1], s2 = csr_src[j + 2], s3 = csr_src[j + 3];
        int s4 = csr_src[j + 4], s5 = csr_src[j + 5], s6 = csr_src[j + 6], s7 = csr_src[j + 7];
        float v0 = bf2f(hs[(size_t)s0 * 32 + lane]);
        float v1 = bf2f(hs[(size_t)s1 * 32 + lane]);
        float v2 = bf2f(hs[(size_t)s2 * 32 + lane]);
        float v3 = bf2f(hs[(size_t)s3 * 32 + lane]);
        float v4 = bf2f(hs[(size_t)s4 * 32 + lane]);
        float v5 = bf2f(hs[(size_t)s5 * 32 + lane]);
        float v6 = bf2f(hs[(size_t)s6 * 32 + lane]);
        float v7 = bf2f(hs[(size_t)s7 * 32 + lane]);
        acc0 += v0; acc1 += v1; acc2 += v2; acc3 += v3;
        acc0 += v4; acc1 += v5; acc2 += v6; acc3 += v7;
    }
    if (j + 3 < end) {
        int s0 = csr_src[j + 0], s1 = csr_src[j + 1], s2 = csr_src[j + 2], s3 = csr_src[j + 3];
        acc0 += bf2f(hs[(size_t)s0 * 32 + lane]);
        acc1 += bf2f(hs[(size_t)s1 * 32 + lane]);
        acc2 += bf2f(hs[(size_t)s2 * 32 + lane]);
        acc3 += bf2f(hs[(size_t)s3 * 32 + lane]);
        j += 4;
    }
    for (; j < end; ++j) acc0 += bf2f(hs[(size_t)csr_src[j] * 32 + lane]);
    float r = ((acc0 + acc1) + (acc2 + acc3)) * dinv[d] + b[lane];
    out[(size_t)d * 32 + lane] = r;
}

extern "C" void kernel_launch(void* const* d_in, const int* in_sizes, int n_in,
                              void* d_out, int out_size, void* d_ws, size_t ws_size,
                              hipStream_t stream) {
    const float* x = (const float*)d_in[0];
    const int* ei = (const int*)d_in[1];
    const float* W1 = (const float*)d_in[2];
    const float* b1 = (const float*)d_in[3];
    const float* W2 = (const float*)d_in[4];
    const float* b2 = (const float*)d_in[5];

    const int N = in_sizes[0] / 128;  // 100000
    const int E = in_sizes[1] / 2;    // 1600000
    const int* src = ei;
    const int* dst = ei + E;
    const int nbk = NBKT(N);          // 782 buckets of 128 dst nodes

    // workspace layout (4-byte units unless noted)
    int* bcnt = (int*)d_ws;                            // nbk (pad 1024)
    int* boffs = bcnt + 1024;                          // nbk+1 (pad 1024)
    int* gcursor = boffs + 1024;                       // nbk (pad 1024)
    float* dinv = (float*)(gcursor + 1024);            // N
    int* offs = (int*)(dinv + ((N + 255) & ~255));     // N+1
    int* entries = offs + ((N + 1 + 255) & ~255);      // E
    int* csr_src = entries + ((E + 255) & ~255);       // E
    unsigned short* h1s = (unsigned short*)(csr_src + ((E + 255) & ~255));  // N*64 bf16
    float* h2 = (float*)(h1s + (size_t)N * 64);        // N*64 fp32
    unsigned short* h3s = h1s;                         // reuse (N*32 bf16)
    float* out = (float*)d_out;

    // 1) bucket histogram -> offsets
    hipMemsetAsync(bcnt, 0, 1024 * 4, stream);
    bhist_kernel<<<(E + BH_CHUNK - 1) / BH_CHUNK, 256, 0, stream>>>(dst, E, nbk, bcnt);
    bscan_kernel<<<1, 1024, 0, stream>>>(bcnt, nbk, E, boffs, gcursor);

    // 2) two-phase node-exact CSR build (bucket2csr also emits dinv)
    binfill_kernel<<<(E + BF_CHUNK - 1) / BF_CHUNK, 256, 0, stream>>>(src, dst, E, nbk, gcursor, entries);
    bucket2csr_kernel<<<nbk, 256, 0, stream>>>(entries, boffs, nbk, offs, csr_src, dinv, N, E);

    // 3) h1s = bf16((x @ W1) * dinv)
    gemm_tile_kernel<128, 64, 64, true><<<(N + 63) / 64, 256, 0, stream>>>(x, W1, dinv, h1s, N);

    // 4) h2 = relu(dinv*(gather h1s) + b1)   (fp32)
    gather64_kernel<true><<<(N + 3) / 4, 256, 0, stream>>>(h1s, dinv, offs, csr_src, b1, h2, N);

    // 5) h3s = bf16((h2 @ W2) * dinv)
    gemm_tile_kernel<64, 32, 128, true><<<(N + 127) / 128, 256, 0, stream>>>(h2, W2, dinv, h3s, N);

    // 6) out = dinv*(gather h3s) + b2   (fp32)
    gather32_kernel<<<(N + 7) / 8, 256, 0, stream>>>(h3s, dinv, offs, csr_src, b2, out, N);
}

// Round 14
// 202.831 us; speedup vs baseline: 6.1177x; 1.0107x over previous
//
#include <hip/hip_runtime.h>

// GCN 2-layer. R14: gathers widened to 16 edges in flight (R13 was 8-wide and
// latency-bound: VALU 40%, fetch at per-XCD compulsory floor 87.7MB, avg node
// = 17 edges = 2 dependent memory rounds). Most nodes now finish in one round.

#define NBKT(n) (((n) + 127) >> 7)

__device__ inline float bf2f(unsigned short u) {
    union { unsigned int i; float f; } v;
    v.i = ((unsigned int)u) << 16;
    return v.f;
}
__device__ inline unsigned short f2bf(float f) {
    union { float f; unsigned int i; } v;
    v.f = f;
    unsigned int u = v.i;
    return (unsigned short)((u + 0x7fff + ((u >> 16) & 1)) >> 16);  // RTN-even
}

// ---------------- bucket histogram (R13 proven) ----------------
#define BH_CHUNK 4096
__global__ void __launch_bounds__(256) bhist_kernel(
        const int* __restrict__ dst, int E, int nbk, int* __restrict__ bcnt) {
    __shared__ int cnt[NBKT(100000)];
    const int t = threadIdx.x;
    const int beg = blockIdx.x * BH_CHUNK;
    const int end = min(E, beg + BH_CHUNK);
    for (int b = t; b < nbk; b += 256) cnt[b] = 0;
    __syncthreads();
    for (int i = beg + t; i < end; i += 256) atomicAdd(&cnt[dst[i] >> 7], 1);
    __syncthreads();
    for (int b = t; b < nbk; b += 256) {
        int c = cnt[b];
        if (c) atomicAdd(&bcnt[b], c);
    }
}

// ---------------- bucket offsets (R13 proven) ----------------
__global__ void bscan_kernel(const int* __restrict__ bcnt, int nbk, int E,
                             int* __restrict__ boffs, int* __restrict__ gcursor) {
    __shared__ int s[1024];
    const int t = threadIdx.x;
    int v = (t < nbk) ? bcnt[t] : 0;
    s[t] = v;
    __syncthreads();
    for (int off = 1; off < 1024; off <<= 1) {
        int x = (t >= off) ? s[t - off] : 0;
        __syncthreads();
        s[t] += x;
        __syncthreads();
    }
    if (t < nbk) {
        int excl = s[t] - v;
        boffs[t] = excl;
        gcursor[t] = excl;
    }
    if (t == 0) boffs[nbk] = E;
}

// ---------------- binfill (R8/R11 proven): entry = (src<<7)|(dst&127) ----------------
#define BF_CHUNK 4096
__global__ void __launch_bounds__(256) binfill_kernel(
        const int* __restrict__ src, const int* __restrict__ dst, int E, int nbk,
        int* __restrict__ gcursor, int* __restrict__ entries) {
    __shared__ int cnt[NBKT(100000)];
    __shared__ int gbase[NBKT(100000)];
    __shared__ int rank[NBKT(100000)];
    const int t = threadIdx.x;
    const int beg = blockIdx.x * BF_CHUNK;
    const int end = min(E, beg + BF_CHUNK);
    for (int b = t; b < nbk; b += 256) cnt[b] = 0;
    __syncthreads();
    for (int i = beg + t; i < end; i += 256) atomicAdd(&cnt[dst[i] >> 7], 1);
    __syncthreads();
    for (int b = t; b < nbk; b += 256) {
        int c = cnt[b];
        gbase[b] = c ? atomicAdd(&gcursor[b], c) : 0;
        rank[b] = 0;
    }
    __syncthreads();
    for (int i = beg + t; i < end; i += 256) {
        int d = dst[i];
        int b = d >> 7;
        int r = atomicAdd(&rank[b], 1);
        entries[gbase[b] + r] = (src[i] << 7) | (d & 127);
    }
}

// ---------------- bucket2csr (R9 proven) + dinv emission (R13) ----------------
__global__ void __launch_bounds__(256) bucket2csr_kernel(
        const int* __restrict__ entries, const int* __restrict__ boffs, int nbk,
        int* __restrict__ offs, int* __restrict__ csr_src, float* __restrict__ dinv,
        int N, int E) {
    __shared__ int cnt[128];
    __shared__ int s[128];
    __shared__ int rank[128];
    const int t = threadIdx.x;
    const int b = blockIdx.x;
    const int beg = boffs[b];
    const int end = boffs[b + 1];
    if (t < 128) { cnt[t] = 0; rank[t] = 0; }
    __syncthreads();
    for (int i = beg + t; i < end; i += 256) atomicAdd(&cnt[entries[i] & 127], 1);
    __syncthreads();
    if (t < 128) s[t] = cnt[t];
    __syncthreads();
    for (int off = 1; off < 128; off <<= 1) {
        int x = 0;
        if (t < 128 && t >= off) x = s[t - off];
        __syncthreads();
        if (t < 128) s[t] += x;
        __syncthreads();
    }
    const int node0 = b * 128;
    if (t < 128 && node0 + t < N) {
        offs[node0 + t] = beg + s[t] - cnt[t];
        dinv[node0 + t] = rsqrtf((float)cnt[t] + 1.0f);  // +1 = self-loop
    }
    if (b == 0 && t == 0) offs[N] = E;
    __syncthreads();
    for (int i = beg + t; i < end; i += 256) {
        int e = entries[i];
        int d = e & 127;
        int r = atomicAdd(&rank[d], 1);
        csr_src[beg + s[d] - cnt[d] + r] = (int)((unsigned)e >> 7);
    }
}

// ---------------- LDS-tiled GEMM (R6 proven), bf16-out option ----------------
#define FMA4(ACC, AV, WV) \
    ACC.x += (AV) * (WV).x; ACC.y += (AV) * (WV).y; ACC.z += (AV) * (WV).z; ACC.w += (AV) * (WV).w;

template <int K, int C, int BR, bool BF16OUT>
__global__ void __launch_bounds__(256) gemm_tile_kernel(
        const float* __restrict__ A, const float* __restrict__ W,
        const float* __restrict__ dinv, void* __restrict__ outv, int N) {
    constexpr int F4R = K / 4;
    constexpr int CG = C / 4;
    static_assert(256 / CG * 4 == BR, "geometry");
    __shared__ float Wl[K * C];
    __shared__ float Al[BR * K];

    const int t = threadIdx.x;
    for (int i = t; i < K * C / 4; i += 256) ((float4*)Wl)[i] = ((const float4*)W)[i];
    const int row0 = blockIdx.x * BR;
    for (int i = t; i < BR * F4R; i += 256) {
        int r = i / F4R, k4 = i % F4R;
        float4 v = make_float4(0.f, 0.f, 0.f, 0.f);
        if (row0 + r < N) v = ((const float4*)(A + (size_t)(row0 + r) * K))[k4];
        *(float4*)(Al + r * K + k4 * 4) = v;
    }
    __syncthreads();

    const int c0 = (t % CG) * 4;
    const int r0 = (t / CG) * 4;
    const float* Ab = Al + r0 * K;

    float4 acc0 = {0, 0, 0, 0}, acc1 = {0, 0, 0, 0}, acc2 = {0, 0, 0, 0}, acc3 = {0, 0, 0, 0};

#pragma unroll 2
    for (int k4 = 0; k4 < K / 4; ++k4) {
        float4 a0 = *(const float4*)(Ab + 0 * K + k4 * 4);
        float4 a1 = *(const float4*)(Ab + 1 * K + k4 * 4);
        float4 a2 = *(const float4*)(Ab + 2 * K + k4 * 4);
        float4 a3 = *(const float4*)(Ab + 3 * K + k4 * 4);
        float4 w0 = *(const float4*)(Wl + (k4 * 4 + 0) * C + c0);
        float4 w1 = *(const float4*)(Wl + (k4 * 4 + 1) * C + c0);
        float4 w2 = *(const float4*)(Wl + (k4 * 4 + 2) * C + c0);
        float4 w3 = *(const float4*)(Wl + (k4 * 4 + 3) * C + c0);
        FMA4(acc0, a0.x, w0) FMA4(acc1, a1.x, w0) FMA4(acc2, a2.x, w0) FMA4(acc3, a3.x, w0)
        FMA4(acc0, a0.y, w1) FMA4(acc1, a1.y, w1) FMA4(acc2, a2.y, w1) FMA4(acc3, a3.y, w1)
        FMA4(acc0, a0.z, w2) FMA4(acc1, a1.z, w2) FMA4(acc2, a2.z, w2) FMA4(acc3, a3.z, w2)
        FMA4(acc0, a0.w, w3) FMA4(acc1, a1.w, w3) FMA4(acc2, a2.w, w3) FMA4(acc3, a3.w, w3)
    }

    const int row = row0 + r0;
#pragma unroll
    for (int i = 0; i < 4; ++i) {
        int rr = row + i;
        if (rr < N) {
            float d = dinv[rr];
            float4 fr = (i == 0) ? acc0 : (i == 1) ? acc1 : (i == 2) ? acc2 : acc3;
            fr.x *= d; fr.y *= d; fr.z *= d; fr.w *= d;
            if (BF16OUT) {
                ushort4 o;
                o.x = f2bf(fr.x); o.y = f2bf(fr.y); o.z = f2bf(fr.z); o.w = f2bf(fr.w);
                *(ushort4*)((unsigned short*)outv + (size_t)rr * C + c0) = o;
            } else {
                *(float4*)((float*)outv + (size_t)rr * C + c0) = fr;
            }
        }
    }
}

// ---------------- gather C=64: one node/wave, 16 edges in flight ----------------
#define G64_LOAD(SS) bf2f(hs[(size_t)(SS) * 64 + lane])
template <bool RELU>
__global__ void __launch_bounds__(256) gather64_kernel(
        const unsigned short* __restrict__ hs, const float* __restrict__ dinv,
        const int* __restrict__ offs, const int* __restrict__ csr_src,
        const float* __restrict__ b, float* __restrict__ out, int N) {
    const int lane = threadIdx.x & 63;
    const int d = blockIdx.x * 4 + (threadIdx.x >> 6);  // wave-uniform
    if (d >= N) return;
    const int beg = offs[d];
    const int end = offs[d + 1];
    float acc0 = G64_LOAD(d);  // self-loop
    float acc1 = 0.f, acc2 = 0.f, acc3 = 0.f;
    int j = beg;
    for (; j + 15 < end; j += 16) {
        int s0 = csr_src[j + 0], s1 = csr_src[j + 1], s2 = csr_src[j + 2], s3 = csr_src[j + 3];
        int s4 = csr_src[j + 4], s5 = csr_src[j + 5], s6 = csr_src[j + 6], s7 = csr_src[j + 7];
        int s8 = csr_src[j + 8], s9 = csr_src[j + 9], sa = csr_src[j + 10], sb = csr_src[j + 11];
        int sc = csr_src[j + 12], sd = csr_src[j + 13], se = csr_src[j + 14], sf = csr_src[j + 15];
        float v0 = G64_LOAD(s0), v1 = G64_LOAD(s1), v2 = G64_LOAD(s2), v3 = G64_LOAD(s3);
        float v4 = G64_LOAD(s4), v5 = G64_LOAD(s5), v6 = G64_LOAD(s6), v7 = G64_LOAD(s7);
        float v8 = G64_LOAD(s8), v9 = G64_LOAD(s9), va = G64_LOAD(sa), vb = G64_LOAD(sb);
        float vc = G64_LOAD(sc), vd = G64_LOAD(sd), ve = G64_LOAD(se), vf = G64_LOAD(sf);
        acc0 += v0; acc1 += v1; acc2 += v2; acc3 += v3;
        acc0 += v4; acc1 += v5; acc2 += v6; acc3 += v7;
        acc0 += v8; acc1 += v9; acc2 += va; acc3 += vb;
        acc0 += vc; acc1 += vd; acc2 += ve; acc3 += vf;
    }
    if (j + 7 < end) {
        int s0 = csr_src[j + 0], s1 = csr_src[j + 1], s2 = csr_src[j + 2], s3 = csr_src[j + 3];
        int s4 = csr_src[j + 4], s5 = csr_src[j + 5], s6 = csr_src[j + 6], s7 = csr_src[j + 7];
        float v0 = G64_LOAD(s0), v1 = G64_LOAD(s1), v2 = G64_LOAD(s2), v3 = G64_LOAD(s3);
        float v4 = G64_LOAD(s4), v5 = G64_LOAD(s5), v6 = G64_LOAD(s6), v7 = G64_LOAD(s7);
        acc0 += v0; acc1 += v1; acc2 += v2; acc3 += v3;
        acc0 += v4; acc1 += v5; acc2 += v6; acc3 += v7;
        j += 8;
    }
    if (j + 3 < end) {
        int s0 = csr_src[j + 0], s1 = csr_src[j + 1], s2 = csr_src[j + 2], s3 = csr_src[j + 3];
        acc0 += G64_LOAD(s0); acc1 += G64_LOAD(s1); acc2 += G64_LOAD(s2); acc3 += G64_LOAD(s3);
        j += 4;
    }
    for (; j < end; ++j) acc0 += G64_LOAD(csr_src[j]);
    float r = ((acc0 + acc1) + (acc2 + acc3)) * dinv[d] + b[lane];
    if (RELU) r = fmaxf(r, 0.f);
    out[(size_t)d * 64 + lane] = r;
}

// ---------------- gather C=32: 2 nodes/wave, 16 edges in flight ----------------
#define G32_LOAD(SS) bf2f(hs[(size_t)(SS) * 32 + lane])
__global__ void __launch_bounds__(256) gather32_kernel(
        const unsigned short* __restrict__ hs, const float* __restrict__ dinv,
        const int* __restrict__ offs, const int* __restrict__ csr_src,
        const float* __restrict__ b, float* __restrict__ out, int N) {
    const int lane = threadIdx.x & 31;
    const int d = blockIdx.x * 8 + (threadIdx.x >> 5);
    if (d >= N) return;
    const int beg = offs[d];
    const int end = offs[d + 1];
    float acc0 = G32_LOAD(d);  // self-loop
    float acc1 = 0.f, acc2 = 0.f, acc3 = 0.f;
    int j = beg;
    for (; j + 15 < end; j += 16) {
        int s0 = csr_src[j + 0], s1 = csr_src[j + 1], s2 = csr_src[j + 2], s3 = csr_src[j + 3];
        int s4 = csr_src[j + 4], s5 = csr_src[j + 5], s6 = csr_src[j + 6], s7 = csr_src[j + 7];
        int s8 = csr_src[j + 8], s9 = csr_src[j + 9], sa = csr_src[j + 10], sb = csr_src[j + 11];
        int sc = csr_src[j + 12], sd = csr_src[j + 13], se = csr_src[j + 14], sf = csr_src[j + 15];
        float v0 = G32_LOAD(s0), v1 = G32_LOAD(s1), v2 = G32_LOAD(s2), v3 = G32_LOAD(s3);
        float v4 = G32_LOAD(s4), v5 = G32_LOAD(s5), v6 = G32_LOAD(s6), v7 = G32_LOAD(s7);
        float v8 = G32_LOAD(s8), v9 = G32_LOAD(s9), va = G32_LOAD(sa), vb = G32_LOAD(sb);
        float vc = G32_LOAD(sc), vd = G32_LOAD(sd), ve = G32_LOAD(se), vf = G32_LOAD(sf);
        acc0 += v0; acc1 += v1; acc2 += v2; acc3 += v3;
        acc0 += v4; acc1 += v5; acc2 += v6; acc3 += v7;
        acc0 += v8; acc1 += v9; acc2 += va; acc3 += vb;
        acc0 += vc; acc1 += vd; acc2 += ve; acc3 += vf;
    }
    if (j + 7 < end) {
        int s0 = csr_src[j + 0], s1 = csr_src[j + 1], s2 = csr_src[j + 2], s3 = csr_src[j + 3];
        int s4 = csr_src[j + 4], s5 = csr_src[j + 5], s6 = csr_src[j + 6], s7 = csr_src[j + 7];
        float v0 = G32_LOAD(s0), v1 = G32_LOAD(s1), v2 = G32_LOAD(s2), v3 = G32_LOAD(s3);
        float v4 = G32_LOAD(s4), v5 = G32_LOAD(s5), v6 = G32_LOAD(s6), v7 = G32_LOAD(s7);
        acc0 += v0; acc1 += v1; acc2 += v2; acc3 += v3;
        acc0 += v4; acc1 += v5; acc2 += v6; acc3 += v7;
        j += 8;
    }
    if (j + 3 < end) {
        int s0 = csr_src[j + 0], s1 = csr_src[j + 1], s2 = csr_src[j + 2], s3 = csr_src[j + 3];
        acc0 += G32_LOAD(s0); acc1 += G32_LOAD(s1); acc2 += G32_LOAD(s2); acc3 += G32_LOAD(s3);
        j += 4;
    }
    for (; j < end; ++j) acc0 += G32_LOAD(csr_src[j]);
    float r = ((acc0 + acc1) + (acc2 + acc3)) * dinv[d] + b[lane];
    out[(size_t)d * 32 + lane] = r;
}

extern "C" void kernel_launch(void* const* d_in, const int* in_sizes, int n_in,
                              void* d_out, int out_size, void* d_ws, size_t ws_size,
                              hipStream_t stream) {
    const float* x = (const float*)d_in[0];
    const int* ei = (const int*)d_in[1];
    const float* W1 = (const float*)d_in[2];
    const float* b1 = (const float*)d_in[3];
    const float* W2 = (const float*)d_in[4];
    const float* b2 = (const float*)d_in[5];

    const int N = in_sizes[0] / 128;  // 100000
    const int E = in_sizes[1] / 2;    // 1600000
    const int* src = ei;
    const int* dst = ei + E;
    const int nbk = NBKT(N);          // 782 buckets of 128 dst nodes

    // workspace layout (4-byte units unless noted)
    int* bcnt = (int*)d_ws;                            // nbk (pad 1024)
    int* boffs = bcnt + 1024;                          // nbk+1 (pad 1024)
    int* gcursor = boffs + 1024;                       // nbk (pad 1024)
    float* dinv = (float*)(gcursor + 1024);            // N
    int* offs = (int*)(dinv + ((N + 255) & ~255));     // N+1
    int* entries = offs + ((N + 1 + 255) & ~255);      // E
    int* csr_src = entries + ((E + 255) & ~255);       // E
    unsigned short* h1s = (unsigned short*)(csr_src + ((E + 255) & ~255));  // N*64 bf16
    float* h2 = (float*)(h1s + (size_t)N * 64);        // N*64 fp32
    unsigned short* h3s = h1s;                         // reuse (N*32 bf16)
    float* out = (float*)d_out;

    // 1) bucket histogram -> offsets
    hipMemsetAsync(bcnt, 0, 1024 * 4, stream);
    bhist_kernel<<<(E + BH_CHUNK - 1) / BH_CHUNK, 256, 0, stream>>>(dst, E, nbk, bcnt);
    bscan_kernel<<<1, 1024, 0, stream>>>(bcnt, nbk, E, boffs, gcursor);

    // 2) two-phase node-exact CSR build (bucket2csr also emits dinv)
    binfill_kernel<<<(E + BF_CHUNK - 1) / BF_CHUNK, 256, 0, stream>>>(src, dst, E, nbk, gcursor, entries);
    bucket2csr_kernel<<<nbk, 256, 0, stream>>>(entries, boffs, nbk, offs, csr_src, dinv, N, E);

    // 3) h1s = bf16((x @ W1) * dinv)
    gemm_tile_kernel<128, 64, 64, true><<<(N + 63) / 64, 256, 0, stream>>>(x, W1, dinv, h1s, N);

    // 4) h2 = relu(dinv*(gather h1s) + b1)   (fp32)
    gather64_kernel<true><<<(N + 3) / 4, 256, 0, stream>>>(h1s, dinv, offs, csr_src, b1, h2, N);

    // 5) h3s = bf16((h2 @ W2) * dinv)
    gemm_tile_kernel<64, 32, 128, true><<<(N + 127) / 128, 256, 0, stream>>>(h2, W2, dinv, h3s, N);

    // 6) out = dinv*(gather h3s) + b2   (fp32)
    gather32_kernel<<<(N + 7) / 8, 256, 0, stream>>>(h3s, dinv, offs, csr_src, b2, out, N);
}